// Round 11
// baseline (168.425 us; speedup 1.0000x reference)
//
#include <hip/hip_runtime.h>

typedef __attribute__((ext_vector_type(8))) short short8;
typedef __attribute__((ext_vector_type(4))) short short4v;
typedef __attribute__((ext_vector_type(4))) float f32x4;

__device__ __forceinline__ short f2bf(float f) {
  unsigned u = __builtin_bit_cast(unsigned, f);
  u = u + 0x7fffu + ((u >> 16) & 1u);
  return (short)(u >> 16);
}

// ---------------- fused pre: GN stats + wcast(wq,wk,wp) + lsum zero
//                  + wvT transpose + bias2
// blocks: 0..1023 GN | 1024..2047 wcast | 2048..2051 lsum0
//         2052..2115 wvT | 2116..2117 bias2
__global__ __launch_bounds__(256) void pre_kernel(
    const float* __restrict__ x, float2* __restrict__ part,
    const float* __restrict__ wq, const float* __restrict__ wk,
    const float* __restrict__ wp, const float* __restrict__ wv,
    const float* __restrict__ bv, const float* __restrict__ bp,
    short* __restrict__ wout, short* __restrict__ wp_bf,
    short* __restrict__ wvT, float* __restrict__ bias2,
    float* __restrict__ lz) {
  const int blk = blockIdx.x, t = threadIdx.x;
  if (blk < 1024) {
    const float* base = x + (long)blk * 8192;
    float s = 0.f, ss = 0.f;
#pragma unroll
    for (int j = 0; j < 8; ++j) {
      float4 v = ((const float4*)base)[t + j * 256];
      s  += v.x + v.y + v.z + v.w;
      ss += v.x * v.x + v.y * v.y + v.z * v.z + v.w * v.w;
    }
    for (int o = 32; o > 0; o >>= 1) { s += __shfl_xor(s, o, 64); ss += __shfl_xor(ss, o, 64); }
    __shared__ float rs[4], rss[4];
    if ((t & 63) == 0) { rs[t >> 6] = s; rss[t >> 6] = ss; }
    __syncthreads();
    if (t == 0) {
      part[blk] = make_float2(rs[0] + rs[1] + rs[2] + rs[3],
                              rss[0] + rss[1] + rss[2] + rss[3]);
    }
  } else if (blk < 2048) {
    int i = (blk - 1024) * 256 + t;  // full 0..262143 coverage
    wout[i]          = f2bf(wq[i]);
    wout[262144 + i] = f2bf(wk[i]);
    wp_bf[i]         = f2bf(wp[i]);
  } else if (blk < 2052) {
    float4* p = (float4*)lz;
    const int base = (blk - 2048) * 1024 + t * 4;
#pragma unroll
    for (int k = 0; k < 4; ++k) p[base + k] = make_float4(0.f, 0.f, 0.f, 0.f);
  } else if (blk < 2116) {
    // wvT[ci][c] = wv[c][ci], 64x64 tile per block
    const int t2 = blk - 2052, tr = t2 >> 3, tc = t2 & 7;
    __shared__ float tile[64][65];
    const int r = t >> 2, q4 = t & 3;
    const float* src = wv + (long)(tr * 64 + r) * 512 + tc * 64 + q4 * 16;
#pragma unroll
    for (int k = 0; k < 4; ++k) {
      float4 v = ((const float4*)src)[k];
      tile[r][q4 * 16 + k * 4 + 0] = v.x;
      tile[r][q4 * 16 + k * 4 + 1] = v.y;
      tile[r][q4 * 16 + k * 4 + 2] = v.z;
      tile[r][q4 * 16 + k * 4 + 3] = v.w;
    }
    __syncthreads();
    const int oc = t >> 2, seg = t & 3;
    short tmp[16];
#pragma unroll
    for (int e = 0; e < 16; ++e) tmp[e] = f2bf(tile[seg * 16 + e][oc]);
    short* dst = wvT + (long)(tc * 64 + oc) * 512 + tr * 64 + seg * 16;
    *(short8*)dst = *(short8*)&tmp[0];
    *(short8*)(dst + 8) = *(short8*)&tmp[8];
  } else {
    // bias2[m] = bp[m] + dot(wp[m,:], bv) ; wave-parallel per row
    const int blk2 = blk - 2116, w = t >> 6, lane = t & 63;
    const float4 b0 = *(const float4*)(bv + lane * 8);
    const float4 b1 = *(const float4*)(bv + lane * 8 + 4);
    for (int idx = 0; idx < 64; ++idx) {
      const int m = blk2 * 256 + w * 64 + idx;
      const float4 a0 = *(const float4*)(wp + (long)m * 512 + lane * 8);
      const float4 a1 = *(const float4*)(wp + (long)m * 512 + lane * 8 + 4);
      float s = a0.x * b0.x + a0.y * b0.y + a0.z * b0.z + a0.w * b0.w
              + a1.x * b1.x + a1.y * b1.y + a1.z * b1.z + a1.w * b1.w;
#pragma unroll
      for (int o = 32; o > 0; o >>= 1) s += __shfl_xor(s, o, 64);
      if (lane == 0) bias2[m] = bp[m] + s;
    }
  }
}

// ---------------- GN pass 2: normalize + transpose to xnt[B,N,C]
#define TP 133
__global__ __launch_bounds__(256) void gn_norm_t(
    const float* __restrict__ x, const float2* __restrict__ part,
    const float* __restrict__ gamma, const float* __restrict__ beta,
    short* __restrict__ xnt) {
  const int blk = blockIdx.x;
  const int nc = blk & 7, g = (blk >> 3) & 7, b = blk >> 6;
  const int t = threadIdx.x;
  float s = 0.f, ss = 0.f;
#pragma unroll
  for (int j = 0; j < 8; ++j) {
    float2 p = part[(b * 8 + g) * 8 + j];
    s += p.x; ss += p.y;
  }
  const float mean = s * (1.f / 65536.f);
  const float var  = ss * (1.f / 65536.f) - mean * mean;
  const float rstd = rsqrtf(var + 1e-5f);

  const float* base = x + (long)(b * 512 + g * 64) * 1024 + nc * 128;
  __shared__ float tile[64][TP];
  const int row = t >> 2, c4 = t & 3;
#pragma unroll
  for (int j = 0; j < 8; ++j) {
    float4 v = *(const float4*)(base + (long)row * 1024 + (c4 + j * 4) * 4);
    *(float4*)&tile[row][(c4 + j * 4) * 4] = v;
  }
  const int cl4 = (t & 15) * 4;
  float ga[4], be[4];
#pragma unroll
  for (int j = 0; j < 4; ++j) {
    float gm = gamma[g * 64 + cl4 + j];
    ga[j] = gm * rstd;
    be[j] = beta[g * 64 + cl4 + j] - mean * ga[j];
  }
  __syncthreads();
  short* outb = xnt + (long)b * 524288 + (long)(nc * 128) * 512 + g * 64 + cl4;
#pragma unroll
  for (int it = 0; it < 8; ++it) {
    const int tok = (t >> 4) + it * 16;
    short4v o;
    o.x = f2bf(tile[cl4 + 0][tok] * ga[0] + be[0]);
    o.y = f2bf(tile[cl4 + 1][tok] * ga[1] + be[1]);
    o.z = f2bf(tile[cl4 + 2][tok] * ga[2] + be[2]);
    o.w = f2bf(tile[cl4 + 3][tok] * ga[3] + be[3]);
    *(short4v*)(outb + (long)tok * 512) = o;
  }
}

// ---------------- GEMM core (proven: single-buffer, 2-barrier, 128x128)
#define BM 128
#define BK 64
enum { EPI_EXP_T = 3, EPI_OUT = 5, EPI_WP = 6 };

__device__ __forceinline__ int swz_idx(int row, int k) {
  return row * 64 + ((((k >> 3) ^ row) & 7) << 3) + (k & 7);
}

__device__ __forceinline__ void gemm_core(
    const short* __restrict__ Ab, const short* __restrict__ Bb,
    short* lds, f32x4 (&acc)[4][4], int m0, int n0, int K, int tid) {
  const int lane = tid & 63, w = tid >> 6;
  const int wm = (w >> 1) * 64, wn = (w & 1) * 64;
  const int rowst = w * 32 + (lane >> 3);
  for (int k0 = 0; k0 < K; k0 += BK) {
    __syncthreads();
#pragma unroll
    for (int it = 0; it < 4; ++it) {
      int ci = w * 4 + it;
      int row = rowst + it * 8;
      int slot = (lane & 7) ^ (row & 7);
      const short* ga = Ab + (long)(m0 + row) * K + k0 + slot * 8;
      __builtin_amdgcn_global_load_lds(
          (const __attribute__((address_space(1))) void*)ga,
          (__attribute__((address_space(3))) void*)(lds + ci * 512), 16, 0, 0);
      const short* gb = Bb + (long)(n0 + row) * K + k0 + slot * 8;
      __builtin_amdgcn_global_load_lds(
          (const __attribute__((address_space(1))) void*)gb,
          (__attribute__((address_space(3))) void*)(lds + 8192 + ci * 512), 16, 0, 0);
    }
    __syncthreads();
#pragma unroll
    for (int kk = 0; kk < 2; ++kk) {
      short8 af[4], bf[4];
      const int kf = kk * 32 + (lane >> 4) * 8;
#pragma unroll
      for (int i = 0; i < 4; ++i) {
        af[i] = *(const short8*)(lds + swz_idx(wm + i * 16 + (lane & 15), kf));
        bf[i] = *(const short8*)(lds + 8192 + swz_idx(wn + i * 16 + (lane & 15), kf));
      }
#pragma unroll
      for (int i = 0; i < 4; ++i)
#pragma unroll
        for (int j = 0; j < 4; ++j)
          acc[i][j] = __builtin_amdgcn_mfma_f32_16x16x32_bf16(af[i], bf[j], acc[i][j], 0, 0, 0);
    }
  }
}

// ---------------- fused Q/K/U projection GEMM
// A = stacked [wq; wk; W'] = [1536,512] bf16. grid (8, 12, 16).
__global__ __launch_bounds__(256, 3) void qku_gemm(
    const short* __restrict__ W, const short* __restrict__ xnt,
    short* __restrict__ q_t, short* __restrict__ k_t, short* __restrict__ u,
    const float* __restrict__ bq, const float* __restrict__ bk) {
  __shared__ short lds[2 * BM * BK];
  const int b = blockIdx.z, y = blockIdx.y;
  const int which = y >> 2;
  const int m0 = y * BM;
  const int mloc0 = m0 - which * 512;
  const int n0 = blockIdx.x * BM;
  const short* Bb = xnt + (long)b * 524288;
  const int tid = threadIdx.x, lane = tid & 63, w = tid >> 6;
  f32x4 acc[4][4] = {};
  gemm_core(W, Bb, lds, acc, m0, n0, 512, tid);

  const int wm = (w >> 1) * 64, wn = (w & 1) * 64;
  const int mb = mloc0 + wm + (lane >> 4) * 4;
  const int nb = n0 + wn + (lane & 15);
  if (which < 2) {
    short* C = (which ? k_t : q_t) + (long)b * 524288;
    const float* bias = which ? bk : bq;
#pragma unroll
    for (int i = 0; i < 4; ++i) {
      int m = mb + i * 16;
      float b0 = bias[m], b1 = bias[m + 1], b2 = bias[m + 2], b3 = bias[m + 3];
#pragma unroll
      for (int j = 0; j < 4; ++j) {
        int n = nb + j * 16;
        short4v o;
        o.x = f2bf(acc[i][j][0] + b0);
        o.y = f2bf(acc[i][j][1] + b1);
        o.z = f2bf(acc[i][j][2] + b2);
        o.w = f2bf(acc[i][j][3] + b3);
        *(short4v*)(C + (long)n * 512 + m) = o;  // [tok][ch]
      }
    }
  } else {
    short* C = u + (long)b * 524288;  // [o][tok], stride 1024
#pragma unroll
    for (int i = 0; i < 4; ++i) {
#pragma unroll
      for (int r = 0; r < 4; ++r) {
        int m = mb + i * 16 + r;
#pragma unroll
        for (int j = 0; j < 4; ++j) {
          int n = nb + j * 16;
          C[(long)m * 1024 + n] = f2bf(acc[i][j][r]);
        }
      }
    }
  }
}

// ---------------- generic GEMM (W' / S-exp / final out)
template <int EPI>
__global__ __launch_bounds__(256, 3) void gemm_bt(
    const short* __restrict__ A, const short* __restrict__ Bt,
    void* __restrict__ Cv, const float* __restrict__ bias,
    const float* __restrict__ resid, float scale,
    int M, int N, int K, long aStr, long bStr, long cStr, long rStr,
    float* __restrict__ lsum) {
  __shared__ short lds[2 * BM * BK];
  const int b = blockIdx.z;
  const short* Ab = A + (long)b * aStr;
  const short* Bb = Bt + (long)b * bStr;
  const int m0 = blockIdx.y * BM, n0 = blockIdx.x * BM;
  const int tid = threadIdx.x, lane = tid & 63, w = tid >> 6;
  f32x4 acc[4][4] = {};
  gemm_core(Ab, Bb, lds, acc, m0, n0, K, tid);

  const int wm = (w >> 1) * 64, wn = (w & 1) * 64;
  const int mb = m0 + wm + (lane >> 4) * 4;
  const int nb = n0 + wn + (lane & 15);
  if constexpr (EPI == EPI_WP) {
    // W'[m][n] bf16, row-major
    short* C = (short*)Cv;
#pragma unroll
    for (int i = 0; i < 4; ++i)
#pragma unroll
      for (int r = 0; r < 4; ++r) {
        int m = mb + i * 16 + r;
#pragma unroll
        for (int j = 0; j < 4; ++j)
          C[(long)m * N + nb + j * 16] = f2bf(acc[i][j][r]);
      }
  } else if constexpr (EPI == EPI_EXP_T) {
    // A=keys, Bt=queries. P' = exp(S*scale) at C[q*M+key], packed 8B;
    // per-query rowsums atomically into lsum[b][q].
    short* C = (short*)Cv + (long)b * cStr;
    float rowsum[4] = {0.f, 0.f, 0.f, 0.f};
#pragma unroll
    for (int j = 0; j < 4; ++j) {
      int n = nb + j * 16;  // query
#pragma unroll
      for (int i = 0; i < 4; ++i) {
        int m = mb + i * 16;  // key
        float e0 = __expf(acc[i][j][0] * scale);
        float e1 = __expf(acc[i][j][1] * scale);
        float e2 = __expf(acc[i][j][2] * scale);
        float e3 = __expf(acc[i][j][3] * scale);
        rowsum[j] += (e0 + e1) + (e2 + e3);
        short4v o;
        o.x = f2bf(e0); o.y = f2bf(e1); o.z = f2bf(e2); o.w = f2bf(e3);
        *(short4v*)(C + (long)n * M + m) = o;
      }
    }
#pragma unroll
    for (int j = 0; j < 4; ++j) {
      rowsum[j] += __shfl_xor(rowsum[j], 16, 64);
      rowsum[j] += __shfl_xor(rowsum[j], 32, 64);
    }
    if (lane < 16) {
#pragma unroll
      for (int j = 0; j < 4; ++j)
        atomicAdd(&lsum[b * 1024 + nb + j * 16], rowsum[j]);
    }
  } else {  // EPI_OUT: A=u[o][j], Bt=P'[i][j]. out = acc/lsum[i] + bias2[o] + x
    float* C = (float*)Cv + (long)b * cStr;
    const float* R = resid + (long)b * rStr;
#pragma unroll
    for (int j = 0; j < 4; ++j) {
      int n = nb + j * 16;  // query i
      float rl = 1.0f / lsum[b * 1024 + n];
#pragma unroll
      for (int i = 0; i < 4; ++i) {
#pragma unroll
        for (int r = 0; r < 4; ++r) {
          int m = mb + i * 16 + r;  // channel o
          C[(long)m * N + n] = acc[i][j][r] * rl + bias[m] + R[(long)m * N + n];
        }
      }
    }
  }
}

// ---------------------------------------------------------------- launch
extern "C" void kernel_launch(void* const* d_in, const int* in_sizes, int n_in,
                              void* d_out, int out_size, void* d_ws, size_t ws_size,
                              hipStream_t stream) {
  const float* x     = (const float*)d_in[0];
  const float* gamma = (const float*)d_in[1];
  const float* beta  = (const float*)d_in[2];
  const float* wq    = (const float*)d_in[3];
  const float* bq    = (const float*)d_in[4];
  const float* wk    = (const float*)d_in[5];
  const float* bk    = (const float*)d_in[6];
  const float* wv    = (const float*)d_in[7];
  const float* bv    = (const float*)d_in[8];
  const float* wp    = (const float*)d_in[9];
  const float* bp    = (const float*)d_in[10];

  char* ws = (char*)d_ws;
  short* wbf   = (short*)ws;                     // [wq;wk;W'] bf16, 1.5 MB
  float* bias2 = (float*)(ws + 1572864l);        // 512 f32
  float* lsum  = (float*)(ws + 1638400l);        // 16x1024 f32, 64 KB
  short* xnt = (short*)(ws + 2097152l);          // [B,N,C] bf16, 16 MB
  short* q_t = (short*)(ws + 18874368l);         // [B,tok,ch]
  short* k_t = (short*)(ws + 35651584l);         // [B,tok,ch]
  short* u   = (short*)(ws + 52428800l);         // [B,o,tok] bf16
  short* Sbf = (short*)(ws + 69206016l);         // [B,N,N] bf16 (P')
  // transient (dead before their regions are overwritten):
  float2* gnpart = (float2*)Sbf;                 // 8 KB (dead before S written)
  short* wp_bf = Sbf + 65536;                    // 512 KB (dead after wprime)
  short* wvT   = Sbf + 65536 + 262144;           // 512 KB (dead after wprime)

  pre_kernel<<<2118, 256, 0, stream>>>(
      x, gnpart, wq, wk, wp, wv, bv, bp, wbf, wp_bf, wvT, bias2, lsum);

  // W' = wp . wv  ([512,512] bf16) via the proven core
  gemm_bt<EPI_WP><<<dim3(4, 4, 1), 256, 0, stream>>>(
      wp_bf, wvT, wbf + 524288, nullptr, nullptr, 1.f, 512, 512, 512,
      0, 0, 0, 0, nullptr);

  gn_norm_t<<<1024, 256, 0, stream>>>(x, gnpart, gamma, beta, xnt);

  qku_gemm<<<dim3(8, 12, 16), 256, 0, stream>>>(
      wbf, xnt, q_t, k_t, u, bq, bk);

  const float iscale = 0.044194173824159216f;  // 1/sqrt(512)
  // P' = exp((k_t . q_t^T)^T * scale), rowsums -> lsum
  gemm_bt<EPI_EXP_T><<<dim3(8, 8, 16), 256, 0, stream>>>(
      k_t, q_t, Sbf, nullptr, nullptr, iscale, 1024, 1024, 512,
      524288, 524288, 1048576, 0, lsum);
  // out[o][i] = (u . P'^T)/lsum[i] + bias2[o] + x
  gemm_bt<EPI_OUT><<<dim3(8, 4, 16), 256, 0, stream>>>(
      u, Sbf, d_out, bias2, x, 1.f, 512, 1024, 1024,
      524288, 1048576, 524288, 524288, lsum);
}

// Round 12
// 134.471 us; speedup vs baseline: 1.2525x; 1.2525x over previous
//
#include <hip/hip_runtime.h>

typedef __attribute__((ext_vector_type(8))) short short8;
typedef __attribute__((ext_vector_type(4))) short short4v;
typedef __attribute__((ext_vector_type(4))) float f32x4;

__device__ __forceinline__ short f2bf(float f) {
  unsigned u = __builtin_bit_cast(unsigned, f);
  u = u + 0x7fffu + ((u >> 16) & 1u);
  return (short)(u >> 16);
}

// ---------------- fused pre: bias2 + wvT + lsum0 + wcast + GN stats
// Latency-bound small sections FIRST (scheduled first), GN bulk last.
// blocks: 0..31 bias2 | 32..95 wvT | 96..99 lsum0
//         100..1123 wcast | 1124..2147 GN stats
__global__ __launch_bounds__(256) void pre_kernel(
    const float* __restrict__ x, float2* __restrict__ part,
    const float* __restrict__ wq, const float* __restrict__ wk,
    const float* __restrict__ wp, const float* __restrict__ wv,
    const float* __restrict__ bv, const float* __restrict__ bp,
    short* __restrict__ wout, short* __restrict__ wp_bf,
    short* __restrict__ wvT, float* __restrict__ bias2,
    float* __restrict__ lz) {
  const int blk = blockIdx.x, t = threadIdx.x;
  if (blk < 32) {
    // bias2[m] = bp[m] + dot(wp[m,:], bv); 16 rows/block, 4 rows/wave
    const int w = t >> 6, lane = t & 63;
    const float4 b0 = *(const float4*)(bv + lane * 8);
    const float4 b1 = *(const float4*)(bv + lane * 8 + 4);
#pragma unroll
    for (int idx = 0; idx < 4; ++idx) {
      const int m = blk * 16 + w * 4 + idx;
      const float4 a0 = *(const float4*)(wp + (long)m * 512 + lane * 8);
      const float4 a1 = *(const float4*)(wp + (long)m * 512 + lane * 8 + 4);
      float s = a0.x * b0.x + a0.y * b0.y + a0.z * b0.z + a0.w * b0.w
              + a1.x * b1.x + a1.y * b1.y + a1.z * b1.z + a1.w * b1.w;
#pragma unroll
      for (int o = 32; o > 0; o >>= 1) s += __shfl_xor(s, o, 64);
      if (lane == 0) bias2[m] = bp[m] + s;
    }
  } else if (blk < 96) {
    // wvT[ci][c] = wv[c][ci], 64x64 tile per block
    const int t2 = blk - 32, tr = t2 >> 3, tc = t2 & 7;
    __shared__ float tile[64][65];
    const int r = t >> 2, q4 = t & 3;
    const float* src = wv + (long)(tr * 64 + r) * 512 + tc * 64 + q4 * 16;
#pragma unroll
    for (int k = 0; k < 4; ++k) {
      float4 v = ((const float4*)src)[k];
      tile[r][q4 * 16 + k * 4 + 0] = v.x;
      tile[r][q4 * 16 + k * 4 + 1] = v.y;
      tile[r][q4 * 16 + k * 4 + 2] = v.z;
      tile[r][q4 * 16 + k * 4 + 3] = v.w;
    }
    __syncthreads();
    const int oc = t >> 2, seg = t & 3;
    short tmp[16];
#pragma unroll
    for (int e = 0; e < 16; ++e) tmp[e] = f2bf(tile[seg * 16 + e][oc]);
    short* dst = wvT + (long)(tc * 64 + oc) * 512 + tr * 64 + seg * 16;
    *(short8*)dst = *(short8*)&tmp[0];
    *(short8*)(dst + 8) = *(short8*)&tmp[8];
  } else if (blk < 100) {
    float4* p = (float4*)lz;
    const int base = (blk - 96) * 1024 + t * 4;
#pragma unroll
    for (int k = 0; k < 4; ++k) p[base + k] = make_float4(0.f, 0.f, 0.f, 0.f);
  } else if (blk < 1124) {
    int i = (blk - 100) * 256 + t;  // full 0..262143 coverage
    wout[i]          = f2bf(wq[i]);
    wout[262144 + i] = f2bf(wk[i]);
    wp_bf[i]         = f2bf(wp[i]);
  } else {
    const int blk2 = blk - 1124;
    const float* base = x + (long)blk2 * 8192;
    float s = 0.f, ss = 0.f;
#pragma unroll
    for (int j = 0; j < 8; ++j) {
      float4 v = ((const float4*)base)[t + j * 256];
      s  += v.x + v.y + v.z + v.w;
      ss += v.x * v.x + v.y * v.y + v.z * v.z + v.w * v.w;
    }
    for (int o = 32; o > 0; o >>= 1) { s += __shfl_xor(s, o, 64); ss += __shfl_xor(ss, o, 64); }
    __shared__ float rs[4], rss[4];
    if ((t & 63) == 0) { rs[t >> 6] = s; rss[t >> 6] = ss; }
    __syncthreads();
    if (t == 0) {
      part[blk2] = make_float2(rs[0] + rs[1] + rs[2] + rs[3],
                               rss[0] + rss[1] + rss[2] + rss[3]);
    }
  }
}

// ---------------- GN pass 2: normalize + transpose to xnt[B,N,C]
#define TP 133
__global__ __launch_bounds__(256) void gn_norm_t(
    const float* __restrict__ x, const float2* __restrict__ part,
    const float* __restrict__ gamma, const float* __restrict__ beta,
    short* __restrict__ xnt) {
  const int blk = blockIdx.x;
  const int nc = blk & 7, g = (blk >> 3) & 7, b = blk >> 6;
  const int t = threadIdx.x;
  float s = 0.f, ss = 0.f;
#pragma unroll
  for (int j = 0; j < 8; ++j) {
    float2 p = part[(b * 8 + g) * 8 + j];
    s += p.x; ss += p.y;
  }
  const float mean = s * (1.f / 65536.f);
  const float var  = ss * (1.f / 65536.f) - mean * mean;
  const float rstd = rsqrtf(var + 1e-5f);

  const float* base = x + (long)(b * 512 + g * 64) * 1024 + nc * 128;
  __shared__ float tile[64][TP];
  const int row = t >> 2, c4 = t & 3;
#pragma unroll
  for (int j = 0; j < 8; ++j) {
    float4 v = *(const float4*)(base + (long)row * 1024 + (c4 + j * 4) * 4);
    *(float4*)&tile[row][(c4 + j * 4) * 4] = v;
  }
  const int cl4 = (t & 15) * 4;
  float ga[4], be[4];
#pragma unroll
  for (int j = 0; j < 4; ++j) {
    float gm = gamma[g * 64 + cl4 + j];
    ga[j] = gm * rstd;
    be[j] = beta[g * 64 + cl4 + j] - mean * ga[j];
  }
  __syncthreads();
  short* outb = xnt + (long)b * 524288 + (long)(nc * 128) * 512 + g * 64 + cl4;
#pragma unroll
  for (int it = 0; it < 8; ++it) {
    const int tok = (t >> 4) + it * 16;
    short4v o;
    o.x = f2bf(tile[cl4 + 0][tok] * ga[0] + be[0]);
    o.y = f2bf(tile[cl4 + 1][tok] * ga[1] + be[1]);
    o.z = f2bf(tile[cl4 + 2][tok] * ga[2] + be[2]);
    o.w = f2bf(tile[cl4 + 3][tok] * ga[3] + be[3]);
    *(short4v*)(outb + (long)tok * 512) = o;
  }
}

// ---------------- GEMM core (proven: single-buffer, 2-barrier, 128x128)
#define BM 128
#define BK 64
enum { EPI_EXP_T = 3, EPI_OUT = 5, EPI_WP = 6 };

__device__ __forceinline__ int swz_idx(int row, int k) {
  return row * 64 + ((((k >> 3) ^ row) & 7) << 3) + (k & 7);
}

__device__ __forceinline__ void gemm_core(
    const short* __restrict__ Ab, const short* __restrict__ Bb,
    short* lds, f32x4 (&acc)[4][4], int m0, int n0, int K, int tid) {
  const int lane = tid & 63, w = tid >> 6;
  const int wm = (w >> 1) * 64, wn = (w & 1) * 64;
  const int rowst = w * 32 + (lane >> 3);
  for (int k0 = 0; k0 < K; k0 += BK) {
    __syncthreads();
#pragma unroll
    for (int it = 0; it < 4; ++it) {
      int ci = w * 4 + it;
      int row = rowst + it * 8;
      int slot = (lane & 7) ^ (row & 7);
      const short* ga = Ab + (long)(m0 + row) * K + k0 + slot * 8;
      __builtin_amdgcn_global_load_lds(
          (const __attribute__((address_space(1))) void*)ga,
          (__attribute__((address_space(3))) void*)(lds + ci * 512), 16, 0, 0);
      const short* gb = Bb + (long)(n0 + row) * K + k0 + slot * 8;
      __builtin_amdgcn_global_load_lds(
          (const __attribute__((address_space(1))) void*)gb,
          (__attribute__((address_space(3))) void*)(lds + 8192 + ci * 512), 16, 0, 0);
    }
    __syncthreads();
#pragma unroll
    for (int kk = 0; kk < 2; ++kk) {
      short8 af[4], bf[4];
      const int kf = kk * 32 + (lane >> 4) * 8;
#pragma unroll
      for (int i = 0; i < 4; ++i) {
        af[i] = *(const short8*)(lds + swz_idx(wm + i * 16 + (lane & 15), kf));
        bf[i] = *(const short8*)(lds + 8192 + swz_idx(wn + i * 16 + (lane & 15), kf));
      }
#pragma unroll
      for (int i = 0; i < 4; ++i)
#pragma unroll
        for (int j = 0; j < 4; ++j)
          acc[i][j] = __builtin_amdgcn_mfma_f32_16x16x32_bf16(af[i], bf[j], acc[i][j], 0, 0, 0);
    }
  }
}

// ---------------- fused Q/K/U projection GEMM
// A = stacked [wq; wk; W'] = [1536,512] bf16. grid (8, 12, 16).
__global__ __launch_bounds__(256, 3) void qku_gemm(
    const short* __restrict__ W, const short* __restrict__ xnt,
    short* __restrict__ q_t, short* __restrict__ k_t, short* __restrict__ u,
    const float* __restrict__ bq, const float* __restrict__ bk) {
  __shared__ short lds[2 * BM * BK];
  const int b = blockIdx.z, y = blockIdx.y;
  const int which = y >> 2;
  const int m0 = y * BM;
  const int mloc0 = m0 - which * 512;
  const int n0 = blockIdx.x * BM;
  const short* Bb = xnt + (long)b * 524288;
  const int tid = threadIdx.x, lane = tid & 63, w = tid >> 6;
  f32x4 acc[4][4] = {};
  gemm_core(W, Bb, lds, acc, m0, n0, 512, tid);

  const int wm = (w >> 1) * 64, wn = (w & 1) * 64;
  const int mb = mloc0 + wm + (lane >> 4) * 4;
  const int nb = n0 + wn + (lane & 15);
  if (which < 2) {
    short* C = (which ? k_t : q_t) + (long)b * 524288;
    const float* bias = which ? bk : bq;
#pragma unroll
    for (int i = 0; i < 4; ++i) {
      int m = mb + i * 16;
      float b0 = bias[m], b1 = bias[m + 1], b2 = bias[m + 2], b3 = bias[m + 3];
#pragma unroll
      for (int j = 0; j < 4; ++j) {
        int n = nb + j * 16;
        short4v o;
        o.x = f2bf(acc[i][j][0] + b0);
        o.y = f2bf(acc[i][j][1] + b1);
        o.z = f2bf(acc[i][j][2] + b2);
        o.w = f2bf(acc[i][j][3] + b3);
        *(short4v*)(C + (long)n * 512 + m) = o;  // [tok][ch]
      }
    }
  } else {
    short* C = u + (long)b * 524288;  // [o][tok], stride 1024
#pragma unroll
    for (int i = 0; i < 4; ++i) {
#pragma unroll
      for (int r = 0; r < 4; ++r) {
        int m = mb + i * 16 + r;
#pragma unroll
        for (int j = 0; j < 4; ++j) {
          int n = nb + j * 16;
          C[(long)m * 1024 + n] = f2bf(acc[i][j][r]);
        }
      }
    }
  }
}

// ---------------- generic GEMM (W' / S-exp / final out)
template <int EPI>
__global__ __launch_bounds__(256, 3) void gemm_bt(
    const short* __restrict__ A, const short* __restrict__ Bt,
    void* __restrict__ Cv, const float* __restrict__ bias,
    const float* __restrict__ resid, float scale,
    int M, int N, int K, long aStr, long bStr, long cStr, long rStr,
    float* __restrict__ lsum) {
  __shared__ short lds[2 * BM * BK];
  const int b = blockIdx.z;
  const short* Ab = A + (long)b * aStr;
  const short* Bb = Bt + (long)b * bStr;
  const int m0 = blockIdx.y * BM, n0 = blockIdx.x * BM;
  const int tid = threadIdx.x, lane = tid & 63, w = tid >> 6;
  f32x4 acc[4][4] = {};
  gemm_core(Ab, Bb, lds, acc, m0, n0, K, tid);

  const int wm = (w >> 1) * 64, wn = (w & 1) * 64;
  const int mb = m0 + wm + (lane >> 4) * 4;
  const int nb = n0 + wn + (lane & 15);
  if constexpr (EPI == EPI_WP) {
    // W'[m][n] bf16, row-major
    short* C = (short*)Cv;
#pragma unroll
    for (int i = 0; i < 4; ++i)
#pragma unroll
      for (int r = 0; r < 4; ++r) {
        int m = mb + i * 16 + r;
#pragma unroll
        for (int j = 0; j < 4; ++j)
          C[(long)m * N + nb + j * 16] = f2bf(acc[i][j][r]);
      }
  } else if constexpr (EPI == EPI_EXP_T) {
    // A=keys, Bt=queries. P' = exp(S*scale) at C[q*M+key], packed 8B;
    // per-query rowsums atomically into lsum[b][q].
    short* C = (short*)Cv + (long)b * cStr;
    float rowsum[4] = {0.f, 0.f, 0.f, 0.f};
#pragma unroll
    for (int j = 0; j < 4; ++j) {
      int n = nb + j * 16;  // query
#pragma unroll
      for (int i = 0; i < 4; ++i) {
        int m = mb + i * 16;  // key
        float e0 = __expf(acc[i][j][0] * scale);
        float e1 = __expf(acc[i][j][1] * scale);
        float e2 = __expf(acc[i][j][2] * scale);
        float e3 = __expf(acc[i][j][3] * scale);
        rowsum[j] += (e0 + e1) + (e2 + e3);
        short4v o;
        o.x = f2bf(e0); o.y = f2bf(e1); o.z = f2bf(e2); o.w = f2bf(e3);
        *(short4v*)(C + (long)n * M + m) = o;
      }
    }
#pragma unroll
    for (int j = 0; j < 4; ++j) {
      rowsum[j] += __shfl_xor(rowsum[j], 16, 64);
      rowsum[j] += __shfl_xor(rowsum[j], 32, 64);
    }
    if (lane < 16) {
#pragma unroll
      for (int j = 0; j < 4; ++j)
        atomicAdd(&lsum[b * 1024 + nb + j * 16], rowsum[j]);
    }
  } else {  // EPI_OUT: A=u[o][j], Bt=P'[i][j]. out = acc/lsum[i] + bias2[o] + x
    float* C = (float*)Cv + (long)b * cStr;
    const float* R = resid + (long)b * rStr;
#pragma unroll
    for (int j = 0; j < 4; ++j) {
      int n = nb + j * 16;  // query i
      float rl = 1.0f / lsum[b * 1024 + n];
#pragma unroll
      for (int i = 0; i < 4; ++i) {
#pragma unroll
        for (int r = 0; r < 4; ++r) {
          int m = mb + i * 16 + r;  // channel o
          C[(long)m * N + n] = acc[i][j][r] * rl + bias[m] + R[(long)m * N + n];
        }
      }
    }
  }
}

// ---------------------------------------------------------------- launch
extern "C" void kernel_launch(void* const* d_in, const int* in_sizes, int n_in,
                              void* d_out, int out_size, void* d_ws, size_t ws_size,
                              hipStream_t stream) {
  const float* x     = (const float*)d_in[0];
  const float* gamma = (const float*)d_in[1];
  const float* beta  = (const float*)d_in[2];
  const float* wq    = (const float*)d_in[3];
  const float* bq    = (const float*)d_in[4];
  const float* wk    = (const float*)d_in[5];
  const float* bk    = (const float*)d_in[6];
  const float* wv    = (const float*)d_in[7];
  const float* bv    = (const float*)d_in[8];
  const float* wp    = (const float*)d_in[9];
  const float* bp    = (const float*)d_in[10];

  char* ws = (char*)d_ws;
  short* wbf   = (short*)ws;                     // [wq;wk;W'] bf16, 1.5 MB
  float* bias2 = (float*)(ws + 1572864l);        // 512 f32
  float* lsum  = (float*)(ws + 1638400l);        // 16x1024 f32, 64 KB
  short* xnt = (short*)(ws + 2097152l);          // [B,N,C] bf16, 16 MB
  short* q_t = (short*)(ws + 18874368l);         // [B,tok,ch]
  short* k_t = (short*)(ws + 35651584l);         // [B,tok,ch]
  short* u   = (short*)(ws + 52428800l);         // [B,o,tok] bf16
  short* Sbf = (short*)(ws + 69206016l);         // [B,N,N] bf16 (P')
  // transient (dead before their regions are overwritten):
  float2* gnpart = (float2*)Sbf;                 // 8 KB (dead before S written)
  short* wp_bf = Sbf + 65536;                    // 512 KB (dead after W' gemm)
  short* wvT   = Sbf + 65536 + 262144;           // 512 KB (dead after W' gemm)

  pre_kernel<<<2148, 256, 0, stream>>>(
      x, gnpart, wq, wk, wp, wv, bv, bp, wbf, wp_bf, wvT, bias2, lsum);

  // W' = wp . wv  ([512,512] bf16) via the proven core
  gemm_bt<EPI_WP><<<dim3(4, 4, 1), 256, 0, stream>>>(
      wp_bf, wvT, wbf + 524288, nullptr, nullptr, 1.f, 512, 512, 512,
      0, 0, 0, 0, nullptr);

  gn_norm_t<<<1024, 256, 0, stream>>>(x, gnpart, gamma, beta, xnt);

  qku_gemm<<<dim3(8, 12, 16), 256, 0, stream>>>(
      wbf, xnt, q_t, k_t, u, bq, bk);

  const float iscale = 0.044194173824159216f;  // 1/sqrt(512)
  // P' = exp((k_t . q_t^T)^T * scale), rowsums -> lsum
  gemm_bt<EPI_EXP_T><<<dim3(8, 8, 16), 256, 0, stream>>>(
      k_t, q_t, Sbf, nullptr, nullptr, iscale, 1024, 1024, 512,
      524288, 524288, 1048576, 0, lsum);
  // out[o][i] = (u . P'^T)/lsum[i] + bias2[o] + x
  gemm_bt<EPI_OUT><<<dim3(8, 4, 16), 256, 0, stream>>>(
      u, Sbf, d_out, bias2, x, 1.f, 512, 1024, 1024,
      524288, 1048576, 524288, 524288, lsum);
}

// Round 13
// 126.919 us; speedup vs baseline: 1.3270x; 1.0595x over previous
//
#include <hip/hip_runtime.h>

typedef __attribute__((ext_vector_type(8))) short short8;
typedef __attribute__((ext_vector_type(4))) short short4v;
typedef __attribute__((ext_vector_type(4))) float f32x4;

__device__ __forceinline__ short f2bf(float f) {
  unsigned u = __builtin_bit_cast(unsigned, f);
  u = u + 0x7fffu + ((u >> 16) & 1u);
  return (short)(u >> 16);
}

// ---------------- fused pre
// blocks: 0..31 bias2 | 32..95 wvT | 96..159 wqT | 160..223 wkT
//         224..227 lsum0 | 228..231 cadd0 | 232..487 wp cast | 488..1511 GN
__global__ __launch_bounds__(256) void pre_kernel(
    const float* __restrict__ x, float2* __restrict__ part,
    const float* __restrict__ wq, const float* __restrict__ wk,
    const float* __restrict__ wp, const float* __restrict__ wv,
    const float* __restrict__ bv, const float* __restrict__ bp,
    short* __restrict__ wp_bf, short* __restrict__ wvT,
    short* __restrict__ wqT, short* __restrict__ wkT,
    float* __restrict__ bias2, float* __restrict__ lsum,
    float* __restrict__ cadd) {
  const int blk = blockIdx.x, t = threadIdx.x;
  if (blk < 32) {
    // bias2[m] = bp[m] + dot(wp[m,:], bv); 16 rows/block, 4 rows/wave
    const int w = t >> 6, lane = t & 63;
    const float4 b0 = *(const float4*)(bv + lane * 8);
    const float4 b1 = *(const float4*)(bv + lane * 8 + 4);
#pragma unroll
    for (int idx = 0; idx < 4; ++idx) {
      const int m = blk * 16 + w * 4 + idx;
      const float4 a0 = *(const float4*)(wp + (long)m * 512 + lane * 8);
      const float4 a1 = *(const float4*)(wp + (long)m * 512 + lane * 8 + 4);
      float s = a0.x * b0.x + a0.y * b0.y + a0.z * b0.z + a0.w * b0.w
              + a1.x * b1.x + a1.y * b1.y + a1.z * b1.z + a1.w * b1.w;
#pragma unroll
      for (int o = 32; o > 0; o >>= 1) s += __shfl_xor(s, o, 64);
      if (lane == 0) bias2[m] = bp[m] + s;
    }
  } else if (blk < 224) {
    // transpose: dst[ci][c] = src[c][ci] (bf16), 64x64 tile per block
    const float* src; short* dst; int t2;
    if (blk < 96)       { t2 = blk - 32;  src = wv; dst = wvT; }
    else if (blk < 160) { t2 = blk - 96;  src = wq; dst = wqT; }
    else                { t2 = blk - 160; src = wk; dst = wkT; }
    const int tr = t2 >> 3, tc = t2 & 7;
    __shared__ float tile[64][65];
    const int r = t >> 2, q4 = t & 3;
    const float* s4 = src + (long)(tr * 64 + r) * 512 + tc * 64 + q4 * 16;
#pragma unroll
    for (int k = 0; k < 4; ++k) {
      float4 v = ((const float4*)s4)[k];
      tile[r][q4 * 16 + k * 4 + 0] = v.x;
      tile[r][q4 * 16 + k * 4 + 1] = v.y;
      tile[r][q4 * 16 + k * 4 + 2] = v.z;
      tile[r][q4 * 16 + k * 4 + 3] = v.w;
    }
    __syncthreads();
    const int oc = t >> 2, seg = t & 3;
    short tmp[16];
#pragma unroll
    for (int e = 0; e < 16; ++e) tmp[e] = f2bf(tile[seg * 16 + e][oc]);
    short* dp = dst + (long)(tc * 64 + oc) * 512 + tr * 64 + seg * 16;
    *(short8*)dp = *(short8*)&tmp[0];
    *(short8*)(dp + 8) = *(short8*)&tmp[8];
  } else if (blk < 228) {
    float4* p = (float4*)lsum;
    const int base = (blk - 224) * 1024 + t * 4;
#pragma unroll
    for (int k = 0; k < 4; ++k) p[base + k] = make_float4(0.f, 0.f, 0.f, 0.f);
  } else if (blk < 232) {
    float4* p = (float4*)cadd;
    const int base = (blk - 228) * 1024 + t * 4;
#pragma unroll
    for (int k = 0; k < 4; ++k) p[base + k] = make_float4(0.f, 0.f, 0.f, 0.f);
  } else if (blk < 488) {
    const int i4 = (blk - 232) * 1024 + t * 4;
    float4 v = *(const float4*)(wp + i4);
    short4v o;
    o.x = f2bf(v.x); o.y = f2bf(v.y); o.z = f2bf(v.z); o.w = f2bf(v.w);
    *(short4v*)(wp_bf + i4) = o;
  } else {
    const int blk2 = blk - 488;
    const float* base = x + (long)blk2 * 8192;
    float s = 0.f, ss = 0.f;
#pragma unroll
    for (int j = 0; j < 8; ++j) {
      float4 v = ((const float4*)base)[t + j * 256];
      s  += v.x + v.y + v.z + v.w;
      ss += v.x * v.x + v.y * v.y + v.z * v.z + v.w * v.w;
    }
    for (int o = 32; o > 0; o >>= 1) { s += __shfl_xor(s, o, 64); ss += __shfl_xor(ss, o, 64); }
    __shared__ float rs[4], rss[4];
    if ((t & 63) == 0) { rs[t >> 6] = s; rss[t >> 6] = ss; }
    __syncthreads();
    if (t == 0) {
      part[blk2] = make_float2(rs[0] + rs[1] + rs[2] + rs[3],
                               rss[0] + rss[1] + rss[2] + rss[3]);
    }
  }
}

// ---------------- GEMM core (proven: single-buffer, 2-barrier, 128x128)
#define BM 128
#define BK 64
enum { EPI_EXP_T = 3, EPI_OUT = 5 };

__device__ __forceinline__ int swz_idx(int row, int k) {
  return row * 64 + ((((k >> 3) ^ row) & 7) << 3) + (k & 7);
}

__device__ __forceinline__ void gemm_core(
    const short* __restrict__ Ab, const short* __restrict__ Bb,
    short* lds, f32x4 (&acc)[4][4], int m0, int n0, int K, int tid) {
  const int lane = tid & 63, w = tid >> 6;
  const int wm = (w >> 1) * 64, wn = (w & 1) * 64;
  const int rowst = w * 32 + (lane >> 3);
  for (int k0 = 0; k0 < K; k0 += BK) {
    __syncthreads();
#pragma unroll
    for (int it = 0; it < 4; ++it) {
      int ci = w * 4 + it;
      int row = rowst + it * 8;
      int slot = (lane & 7) ^ (row & 7);
      const short* ga = Ab + (long)(m0 + row) * K + k0 + slot * 8;
      __builtin_amdgcn_global_load_lds(
          (const __attribute__((address_space(1))) void*)ga,
          (__attribute__((address_space(3))) void*)(lds + ci * 512), 16, 0, 0);
      const short* gb = Bb + (long)(n0 + row) * K + k0 + slot * 8;
      __builtin_amdgcn_global_load_lds(
          (const __attribute__((address_space(1))) void*)gb,
          (__attribute__((address_space(3))) void*)(lds + 8192 + ci * 512), 16, 0, 0);
    }
    __syncthreads();
#pragma unroll
    for (int kk = 0; kk < 2; ++kk) {
      short8 af[4], bf[4];
      const int kf = kk * 32 + (lane >> 4) * 8;
#pragma unroll
      for (int i = 0; i < 4; ++i) {
        af[i] = *(const short8*)(lds + swz_idx(wm + i * 16 + (lane & 15), kf));
        bf[i] = *(const short8*)(lds + 8192 + swz_idx(wn + i * 16 + (lane & 15), kf));
      }
#pragma unroll
      for (int i = 0; i < 4; ++i)
#pragma unroll
        for (int j = 0; j < 4; ++j)
          acc[i][j] = __builtin_amdgcn_mfma_f32_16x16x32_bf16(af[i], bf[j], acc[i][j], 0, 0, 0);
    }
  }
}

// ---------------- W2 = wq^T.wk and W' = wp.wv (stacked [1024,512]) + v1
// grid (4,10): y 0..3 -> W2 m-tiles; y 4..7 -> W' m-tiles; y 8..9 -> v1.
__global__ __launch_bounds__(256, 3) void wgemm_kernel(
    const short* __restrict__ wqT, const short* __restrict__ wkT,
    const short* __restrict__ wp_bf, const short* __restrict__ wvT,
    const float* __restrict__ bq, short* __restrict__ Wst,
    float* __restrict__ v1) {
  __shared__ short lds[2 * BM * BK];
  const int y = blockIdx.y, tid = threadIdx.x;
  if (y < 8) {
    const int which = y >> 2;
    const short* A  = which ? wp_bf : wqT;
    const short* Bt = which ? wvT   : wkT;
    const int m0 = (y & 3) * 128, n0 = blockIdx.x * 128;
    f32x4 acc[4][4] = {};
    gemm_core(A, Bt, lds, acc, m0, n0, 512, tid);
    const int lane = tid & 63, w = tid >> 6;
    const int wm = (w >> 1) * 64, wn = (w & 1) * 64;
    const int mb = m0 + wm + (lane >> 4) * 4;
    const int nb = n0 + wn + (lane & 15);
    short* C = Wst + which * 262144;
#pragma unroll
    for (int i = 0; i < 4; ++i)
#pragma unroll
      for (int r = 0; r < 4; ++r) {
        int m = mb + i * 16 + r;
#pragma unroll
        for (int j = 0; j < 4; ++j)
          C[(long)m * 512 + nb + j * 16] = f2bf(acc[i][j][r]);
      }
  } else {
    // v1[c] = dot(wkT[c,:], bq); 64 rows/block, 16 rows/wave
    const int w = tid >> 6, lane = tid & 63;
    const int base_r = ((y - 8) * 4 + blockIdx.x) * 64;
    const float4 b0 = *(const float4*)(bq + lane * 8);
    const float4 b1 = *(const float4*)(bq + lane * 8 + 4);
#pragma unroll
    for (int idx = 0; idx < 16; ++idx) {
      const int c = base_r + w * 16 + idx;
      const short8 a = *(const short8*)(wkT + (long)c * 512 + lane * 8);
      float s = 0.f;
      float av[8];
#pragma unroll
      for (int e = 0; e < 8; ++e)
        av[e] = __builtin_bit_cast(float, ((unsigned)(unsigned short)a[e]) << 16);
      s = av[0] * b0.x + av[1] * b0.y + av[2] * b0.z + av[3] * b0.w
        + av[4] * b1.x + av[5] * b1.y + av[6] * b1.z + av[7] * b1.w;
#pragma unroll
      for (int o = 32; o > 0; o >>= 1) s += __shfl_xor(s, o, 64);
      if (lane == 0) v1[c] = s;
    }
  }
}

// ---------------- GN pass 2: normalize + transpose + cadd accumulation
#define TP 133
__global__ __launch_bounds__(256) void gn_norm_t(
    const float* __restrict__ x, const float2* __restrict__ part,
    const float* __restrict__ gamma, const float* __restrict__ beta,
    const float* __restrict__ v1, short* __restrict__ xnt,
    float* __restrict__ cadd) {
  const int blk = blockIdx.x;
  const int nc = blk & 7, g = (blk >> 3) & 7, b = blk >> 6;
  const int t = threadIdx.x;
  float s = 0.f, ss = 0.f;
#pragma unroll
  for (int j = 0; j < 8; ++j) {
    float2 p = part[(b * 8 + g) * 8 + j];
    s += p.x; ss += p.y;
  }
  const float mean = s * (1.f / 65536.f);
  const float var  = ss * (1.f / 65536.f) - mean * mean;
  const float rstd = rsqrtf(var + 1e-5f);

  const float* base = x + (long)(b * 512 + g * 64) * 1024 + nc * 128;
  __shared__ float tile[64][TP];
  const int row = t >> 2, c4 = t & 3;
#pragma unroll
  for (int j = 0; j < 8; ++j) {
    float4 v = *(const float4*)(base + (long)row * 1024 + (c4 + j * 4) * 4);
    *(float4*)&tile[row][(c4 + j * 4) * 4] = v;
  }
  const int cl4 = (t & 15) * 4;
  float ga[4], be[4];
#pragma unroll
  for (int j = 0; j < 4; ++j) {
    float gm = gamma[g * 64 + cl4 + j];
    ga[j] = gm * rstd;
    be[j] = beta[g * 64 + cl4 + j] - mean * ga[j];
  }
  const float4 v1c = *(const float4*)(v1 + g * 64 + cl4);
  __syncthreads();
  short* outb = xnt + (long)b * 524288 + (long)(nc * 128) * 512 + g * 64 + cl4;
  float* cb = cadd + b * 1024 + nc * 128;
#pragma unroll
  for (int it = 0; it < 8; ++it) {
    const int tok = (t >> 4) + it * 16;
    float x0 = tile[cl4 + 0][tok] * ga[0] + be[0];
    float x1 = tile[cl4 + 1][tok] * ga[1] + be[1];
    float x2 = tile[cl4 + 2][tok] * ga[2] + be[2];
    float x3 = tile[cl4 + 3][tok] * ga[3] + be[3];
    short4v o;
    o.x = f2bf(x0); o.y = f2bf(x1); o.z = f2bf(x2); o.w = f2bf(x3);
    *(short4v*)(outb + (long)tok * 512) = o;
    float p = v1c.x * x0 + v1c.y * x1 + v1c.z * x2 + v1c.w * x3;
    p += __shfl_xor(p, 1, 64); p += __shfl_xor(p, 2, 64);
    p += __shfl_xor(p, 4, 64); p += __shfl_xor(p, 8, 64);
    if ((t & 15) == 0) atomicAdd(&cb[tok], p);
  }
}

// ---------------- fused Z/U projection GEMM
// A = stacked [W2; W'] = [1024,512] bf16. grid (8, 8, 16).
// y 0..3 -> z_t[tok][c] (trans packed, no bias); y 4..7 -> u[o][tok].
__global__ __launch_bounds__(256, 3) void zu_gemm(
    const short* __restrict__ W, const short* __restrict__ xnt,
    short* __restrict__ z_t, short* __restrict__ u) {
  __shared__ short lds[2 * BM * BK];
  const int b = blockIdx.z, y = blockIdx.y;
  const int which = y >> 2;
  const int m0 = y * BM;
  const int mloc0 = m0 - which * 512;
  const int n0 = blockIdx.x * BM;
  const short* Bb = xnt + (long)b * 524288;
  const int tid = threadIdx.x, lane = tid & 63, w = tid >> 6;
  f32x4 acc[4][4] = {};
  gemm_core(W, Bb, lds, acc, m0, n0, 512, tid);

  const int wm = (w >> 1) * 64, wn = (w & 1) * 64;
  const int mb = mloc0 + wm + (lane >> 4) * 4;
  const int nb = n0 + wn + (lane & 15);
  if (which == 0) {
    short* C = z_t + (long)b * 524288;
#pragma unroll
    for (int i = 0; i < 4; ++i) {
      int m = mb + i * 16;
#pragma unroll
      for (int j = 0; j < 4; ++j) {
        int n = nb + j * 16;
        short4v o;
        o.x = f2bf(acc[i][j][0]);
        o.y = f2bf(acc[i][j][1]);
        o.z = f2bf(acc[i][j][2]);
        o.w = f2bf(acc[i][j][3]);
        *(short4v*)(C + (long)n * 512 + m) = o;  // [tok][c]
      }
    }
  } else {
    short* C = u + (long)b * 524288;  // [o][tok], stride 1024
#pragma unroll
    for (int i = 0; i < 4; ++i) {
#pragma unroll
      for (int r = 0; r < 4; ++r) {
        int m = mb + i * 16 + r;
#pragma unroll
        for (int j = 0; j < 4; ++j) {
          int n = nb + j * 16;
          C[(long)m * 1024 + n] = f2bf(acc[i][j][r]);
        }
      }
    }
  }
}

// ---------------- generic GEMM (S-exp / final out)
template <int EPI>
__global__ __launch_bounds__(256, 3) void gemm_bt(
    const short* __restrict__ A, const short* __restrict__ Bt,
    void* __restrict__ Cv, const float* __restrict__ bias,
    const float* __restrict__ resid, float scale,
    int M, int N, int K, long aStr, long bStr, long cStr, long rStr,
    float* __restrict__ lsum, const float* __restrict__ cadd) {
  __shared__ short lds[2 * BM * BK];
  const int b = blockIdx.z;
  const short* Ab = A + (long)b * aStr;
  const short* Bb = Bt + (long)b * bStr;
  const int m0 = blockIdx.y * BM, n0 = blockIdx.x * BM;
  const int tid = threadIdx.x, lane = tid & 63, w = tid >> 6;
  f32x4 acc[4][4] = {};
  gemm_core(Ab, Bb, lds, acc, m0, n0, K, tid);

  const int wm = (w >> 1) * 64, wn = (w & 1) * 64;
  const int mb = m0 + wm + (lane >> 4) * 4;
  const int nb = n0 + wn + (lane & 15);
  if constexpr (EPI == EPI_EXP_T) {
    // A=z_t (rows=key tokens), Bt=xnt (rows=query tokens).
    // P'[q][key] = exp((S + cadd[key]) * scale); rowsums -> lsum[b][q].
    short* C = (short*)Cv + (long)b * cStr;
    float4 ca[4];
#pragma unroll
    for (int i = 0; i < 4; ++i)
      ca[i] = *(const float4*)(cadd + b * 1024 + mb + i * 16);
    float rowsum[4] = {0.f, 0.f, 0.f, 0.f};
#pragma unroll
    for (int j = 0; j < 4; ++j) {
      int n = nb + j * 16;  // query
#pragma unroll
      for (int i = 0; i < 4; ++i) {
        int m = mb + i * 16;  // key
        float e0 = __expf((acc[i][j][0] + ca[i].x) * scale);
        float e1 = __expf((acc[i][j][1] + ca[i].y) * scale);
        float e2 = __expf((acc[i][j][2] + ca[i].z) * scale);
        float e3 = __expf((acc[i][j][3] + ca[i].w) * scale);
        rowsum[j] += (e0 + e1) + (e2 + e3);
        short4v o;
        o.x = f2bf(e0); o.y = f2bf(e1); o.z = f2bf(e2); o.w = f2bf(e3);
        *(short4v*)(C + (long)n * M + m) = o;
      }
    }
#pragma unroll
    for (int j = 0; j < 4; ++j) {
      rowsum[j] += __shfl_xor(rowsum[j], 16, 64);
      rowsum[j] += __shfl_xor(rowsum[j], 32, 64);
    }
    if (lane < 16) {
#pragma unroll
      for (int j = 0; j < 4; ++j)
        atomicAdd(&lsum[b * 1024 + nb + j * 16], rowsum[j]);
    }
  } else {  // EPI_OUT: A=u[o][j], Bt=P'[i][j]. out = acc/lsum[i] + bias2[o] + x
    float* C = (float*)Cv + (long)b * cStr;
    const float* R = resid + (long)b * rStr;
#pragma unroll
    for (int j = 0; j < 4; ++j) {
      int n = nb + j * 16;  // query i
      float rl = 1.0f / lsum[b * 1024 + n];
#pragma unroll
      for (int i = 0; i < 4; ++i) {
#pragma unroll
        for (int r = 0; r < 4; ++r) {
          int m = mb + i * 16 + r;  // channel o
          C[(long)m * N + n] = acc[i][j][r] * rl + bias[m] + R[(long)m * N + n];
        }
      }
    }
  }
}

// ---------------------------------------------------------------- launch
extern "C" void kernel_launch(void* const* d_in, const int* in_sizes, int n_in,
                              void* d_out, int out_size, void* d_ws, size_t ws_size,
                              hipStream_t stream) {
  const float* x     = (const float*)d_in[0];
  const float* gamma = (const float*)d_in[1];
  const float* beta  = (const float*)d_in[2];
  const float* wq    = (const float*)d_in[3];
  const float* bq    = (const float*)d_in[4];
  const float* wk    = (const float*)d_in[5];
  const float* bk    = (const float*)d_in[6];
  const float* wv    = (const float*)d_in[7];
  const float* bv    = (const float*)d_in[8];
  const float* wp    = (const float*)d_in[9];
  const float* bp    = (const float*)d_in[10];
  (void)bk;  // wq^T.bk term is query-constant -> softmax-invariant, drops out

  char* ws = (char*)d_ws;
  short* Wst   = (short*)ws;                     // [W2; W'] bf16, 1 MB
  float* bias2 = (float*)(ws + 1572864l);        // 512 f32
  float* lsum  = (float*)(ws + 1638400l);        // 16x1024 f32
  float* v1    = (float*)(ws + 1703936l);        // 512 f32
  float* cadd  = (float*)(ws + 1708032l);        // 16x1024 f32
  short* xnt = (short*)(ws + 2097152l);          // [B,N,C] bf16, 16 MB
  short* z_t = (short*)(ws + 18874368l);         // [B,tok,c]
  short* u   = (short*)(ws + 52428800l);         // [B,o,tok] bf16
  short* Sbf = (short*)(ws + 69206016l);         // [B,N,N] bf16 (P')
  // transient (all dead before sexp writes Sbf):
  float2* gnpart = (float2*)Sbf;                 // 8 KB
  short* wp_bf = Sbf + 65536;                    // 512 KB
  short* wvT   = Sbf + 327680;                   // 512 KB
  short* wqT   = Sbf + 589824;                   // 512 KB
  short* wkT   = Sbf + 851968;                   // 512 KB

  pre_kernel<<<1512, 256, 0, stream>>>(
      x, gnpart, wq, wk, wp, wv, bv, bp, wp_bf, wvT, wqT, wkT,
      bias2, lsum, cadd);

  wgemm_kernel<<<dim3(4, 10), 256, 0, stream>>>(
      wqT, wkT, wp_bf, wvT, bq, Wst, v1);

  gn_norm_t<<<1024, 256, 0, stream>>>(x, gnpart, gamma, beta, v1, xnt, cadd);

  zu_gemm<<<dim3(8, 8, 16), 256, 0, stream>>>(Wst, xnt, z_t, u);

  const float iscale = 0.044194173824159216f;  // 1/sqrt(512)
  // P' = exp((z_t . xnt^T + cadd)^T * scale), rowsums -> lsum
  gemm_bt<EPI_EXP_T><<<dim3(8, 8, 16), 256, 0, stream>>>(
      z_t, xnt, Sbf, nullptr, nullptr, iscale, 1024, 1024, 512,
      524288, 524288, 1048576, 0, lsum, cadd);
  // out[o][i] = (u . P'^T)/lsum[i] + bias2[o] + x
  gemm_bt<EPI_OUT><<<dim3(8, 4, 16), 256, 0, stream>>>(
      u, Sbf, d_out, bias2, x, 1.f, 512, 1024, 1024,
      524288, 1048576, 524288, 524288, lsum, nullptr);
}

// Round 14
// 118.033 us; speedup vs baseline: 1.4269x; 1.0753x over previous
//
#include <hip/hip_runtime.h>

typedef __attribute__((ext_vector_type(8))) short short8;
typedef __attribute__((ext_vector_type(4))) short short4v;
typedef __attribute__((ext_vector_type(4))) float f32x4;

__device__ __forceinline__ short f2bf(float f) {
  unsigned u = __builtin_bit_cast(unsigned, f);
  u = u + 0x7fffu + ((u >> 16) & 1u);
  return (short)(u >> 16);
}

// XCD-aware remap: hardware round-robins blockIdx across 8 XCDs; give XCD k
// a contiguous logical chunk. Requires gridDim.x % 8 == 0 (bijective form).
__device__ __forceinline__ int xcd_swz() {
  const int cpx = gridDim.x >> 3;
  return (blockIdx.x & 7) * cpx + (blockIdx.x >> 3);
}

// ---------------- fused pre
// blocks: 0..31 bias2 | 32..95 wvT | 96..159 wqT | 160..223 wkT
//         224..227 lsum0 | 228..231 cadd0 | 232..487 wp cast | 488..1511 GN
__global__ __launch_bounds__(256) void pre_kernel(
    const float* __restrict__ x, float2* __restrict__ part,
    const float* __restrict__ wq, const float* __restrict__ wk,
    const float* __restrict__ wp, const float* __restrict__ wv,
    const float* __restrict__ bv, const float* __restrict__ bp,
    short* __restrict__ wp_bf, short* __restrict__ wvT,
    short* __restrict__ wqT, short* __restrict__ wkT,
    float* __restrict__ bias2, float* __restrict__ lsum,
    float* __restrict__ cadd) {
  const int blk = blockIdx.x, t = threadIdx.x;
  if (blk < 32) {
    const int w = t >> 6, lane = t & 63;
    const float4 b0 = *(const float4*)(bv + lane * 8);
    const float4 b1 = *(const float4*)(bv + lane * 8 + 4);
#pragma unroll
    for (int idx = 0; idx < 4; ++idx) {
      const int m = blk * 16 + w * 4 + idx;
      const float4 a0 = *(const float4*)(wp + (long)m * 512 + lane * 8);
      const float4 a1 = *(const float4*)(wp + (long)m * 512 + lane * 8 + 4);
      float s = a0.x * b0.x + a0.y * b0.y + a0.z * b0.z + a0.w * b0.w
              + a1.x * b1.x + a1.y * b1.y + a1.z * b1.z + a1.w * b1.w;
#pragma unroll
      for (int o = 32; o > 0; o >>= 1) s += __shfl_xor(s, o, 64);
      if (lane == 0) bias2[m] = bp[m] + s;
    }
  } else if (blk < 224) {
    const float* src; short* dst; int t2;
    if (blk < 96)       { t2 = blk - 32;  src = wv; dst = wvT; }
    else if (blk < 160) { t2 = blk - 96;  src = wq; dst = wqT; }
    else                { t2 = blk - 160; src = wk; dst = wkT; }
    const int tr = t2 >> 3, tc = t2 & 7;
    __shared__ float tile[64][65];
    const int r = t >> 2, q4 = t & 3;
    const float* s4 = src + (long)(tr * 64 + r) * 512 + tc * 64 + q4 * 16;
#pragma unroll
    for (int k = 0; k < 4; ++k) {
      float4 v = ((const float4*)s4)[k];
      tile[r][q4 * 16 + k * 4 + 0] = v.x;
      tile[r][q4 * 16 + k * 4 + 1] = v.y;
      tile[r][q4 * 16 + k * 4 + 2] = v.z;
      tile[r][q4 * 16 + k * 4 + 3] = v.w;
    }
    __syncthreads();
    const int oc = t >> 2, seg = t & 3;
    short tmp[16];
#pragma unroll
    for (int e = 0; e < 16; ++e) tmp[e] = f2bf(tile[seg * 16 + e][oc]);
    short* dp = dst + (long)(tc * 64 + oc) * 512 + tr * 64 + seg * 16;
    *(short8*)dp = *(short8*)&tmp[0];
    *(short8*)(dp + 8) = *(short8*)&tmp[8];
  } else if (blk < 228) {
    float4* p = (float4*)lsum;
    const int base = (blk - 224) * 1024 + t * 4;
#pragma unroll
    for (int k = 0; k < 4; ++k) p[base + k] = make_float4(0.f, 0.f, 0.f, 0.f);
  } else if (blk < 232) {
    float4* p = (float4*)cadd;
    const int base = (blk - 228) * 1024 + t * 4;
#pragma unroll
    for (int k = 0; k < 4; ++k) p[base + k] = make_float4(0.f, 0.f, 0.f, 0.f);
  } else if (blk < 488) {
    const int i4 = (blk - 232) * 1024 + t * 4;
    float4 v = *(const float4*)(wp + i4);
    short4v o;
    o.x = f2bf(v.x); o.y = f2bf(v.y); o.z = f2bf(v.z); o.w = f2bf(v.w);
    *(short4v*)(wp_bf + i4) = o;
  } else {
    const int blk2 = blk - 488;
    const float* base = x + (long)blk2 * 8192;
    float s = 0.f, ss = 0.f;
#pragma unroll
    for (int j = 0; j < 8; ++j) {
      float4 v = ((const float4*)base)[t + j * 256];
      s  += v.x + v.y + v.z + v.w;
      ss += v.x * v.x + v.y * v.y + v.z * v.z + v.w * v.w;
    }
    for (int o = 32; o > 0; o >>= 1) { s += __shfl_xor(s, o, 64); ss += __shfl_xor(ss, o, 64); }
    __shared__ float rs[4], rss[4];
    if ((t & 63) == 0) { rs[t >> 6] = s; rss[t >> 6] = ss; }
    __syncthreads();
    if (t == 0) {
      part[blk2] = make_float2(rs[0] + rs[1] + rs[2] + rs[3],
                               rss[0] + rss[1] + rss[2] + rss[3]);
    }
  }
}

// ---------------- GEMM core (proven: single-buffer, 2-barrier, 128x128)
#define BM 128
#define BK 64
enum { EPI_EXP_T = 3, EPI_OUT = 5 };

__device__ __forceinline__ int swz_idx(int row, int k) {
  return row * 64 + ((((k >> 3) ^ row) & 7) << 3) + (k & 7);
}

__device__ __forceinline__ void gemm_core(
    const short* __restrict__ Ab, const short* __restrict__ Bb,
    short* lds, f32x4 (&acc)[4][4], int m0, int n0, int K, int tid) {
  const int lane = tid & 63, w = tid >> 6;
  const int wm = (w >> 1) * 64, wn = (w & 1) * 64;
  const int rowst = w * 32 + (lane >> 3);
  for (int k0 = 0; k0 < K; k0 += BK) {
    __syncthreads();
#pragma unroll
    for (int it = 0; it < 4; ++it) {
      int ci = w * 4 + it;
      int row = rowst + it * 8;
      int slot = (lane & 7) ^ (row & 7);
      const short* ga = Ab + (long)(m0 + row) * K + k0 + slot * 8;
      __builtin_amdgcn_global_load_lds(
          (const __attribute__((address_space(1))) void*)ga,
          (__attribute__((address_space(3))) void*)(lds + ci * 512), 16, 0, 0);
      const short* gb = Bb + (long)(n0 + row) * K + k0 + slot * 8;
      __builtin_amdgcn_global_load_lds(
          (const __attribute__((address_space(1))) void*)gb,
          (__attribute__((address_space(3))) void*)(lds + 8192 + ci * 512), 16, 0, 0);
    }
    __syncthreads();
#pragma unroll
    for (int kk = 0; kk < 2; ++kk) {
      short8 af[4], bf[4];
      const int kf = kk * 32 + (lane >> 4) * 8;
#pragma unroll
      for (int i = 0; i < 4; ++i) {
        af[i] = *(const short8*)(lds + swz_idx(wm + i * 16 + (lane & 15), kf));
        bf[i] = *(const short8*)(lds + 8192 + swz_idx(wn + i * 16 + (lane & 15), kf));
      }
#pragma unroll
      for (int i = 0; i < 4; ++i)
#pragma unroll
        for (int j = 0; j < 4; ++j)
          acc[i][j] = __builtin_amdgcn_mfma_f32_16x16x32_bf16(af[i], bf[j], acc[i][j], 0, 0, 0);
    }
  }
}

// ---------------- W2 = wq^T.wk and W' = wp.wv (stacked [1024,512]) + v1
__global__ __launch_bounds__(256, 3) void wgemm_kernel(
    const short* __restrict__ wqT, const short* __restrict__ wkT,
    const short* __restrict__ wp_bf, const short* __restrict__ wvT,
    const float* __restrict__ bq, short* __restrict__ Wst,
    float* __restrict__ v1) {
  __shared__ short lds[2 * BM * BK];
  const int y = blockIdx.y, tid = threadIdx.x;
  if (y < 8) {
    const int which = y >> 2;
    const short* A  = which ? wp_bf : wqT;
    const short* Bt = which ? wvT   : wkT;
    const int m0 = (y & 3) * 128, n0 = blockIdx.x * 128;
    f32x4 acc[4][4] = {};
    gemm_core(A, Bt, lds, acc, m0, n0, 512, tid);
    const int lane = tid & 63, w = tid >> 6;
    const int wm = (w >> 1) * 64, wn = (w & 1) * 64;
    const int mb = m0 + wm + (lane >> 4) * 4;
    const int nb = n0 + wn + (lane & 15);
    short* C = Wst + which * 262144;
#pragma unroll
    for (int i = 0; i < 4; ++i)
#pragma unroll
      for (int r = 0; r < 4; ++r) {
        int m = mb + i * 16 + r;
#pragma unroll
        for (int j = 0; j < 4; ++j)
          C[(long)m * 512 + nb + j * 16] = f2bf(acc[i][j][r]);
      }
  } else {
    // v1[c] = dot(wkT[c,:], bq); 64 rows/block, 16 rows/wave
    const int w = tid >> 6, lane = tid & 63;
    const int base_r = ((y - 8) * 4 + blockIdx.x) * 64;
    const float4 b0 = *(const float4*)(bq + lane * 8);
    const float4 b1 = *(const float4*)(bq + lane * 8 + 4);
#pragma unroll
    for (int idx = 0; idx < 16; ++idx) {
      const int c = base_r + w * 16 + idx;
      const short8 a = *(const short8*)(wkT + (long)c * 512 + lane * 8);
      float av[8];
#pragma unroll
      for (int e = 0; e < 8; ++e)
        av[e] = __builtin_bit_cast(float, ((unsigned)(unsigned short)a[e]) << 16);
      float s = av[0] * b0.x + av[1] * b0.y + av[2] * b0.z + av[3] * b0.w
              + av[4] * b1.x + av[5] * b1.y + av[6] * b1.z + av[7] * b1.w;
#pragma unroll
      for (int o = 32; o > 0; o >>= 1) s += __shfl_xor(s, o, 64);
      if (lane == 0) v1[c] = s;
    }
  }
}

// ---------------- GN pass 2: normalize + transpose + cadd accumulation
#define TP 133
__global__ __launch_bounds__(256) void gn_norm_t(
    const float* __restrict__ x, const float2* __restrict__ part,
    const float* __restrict__ gamma, const float* __restrict__ beta,
    const float* __restrict__ v1, short* __restrict__ xnt,
    float* __restrict__ cadd) {
  const int blk = blockIdx.x;
  const int nc = blk & 7, g = (blk >> 3) & 7, b = blk >> 6;
  const int t = threadIdx.x;
  float s = 0.f, ss = 0.f;
#pragma unroll
  for (int j = 0; j < 8; ++j) {
    float2 p = part[(b * 8 + g) * 8 + j];
    s += p.x; ss += p.y;
  }
  const float mean = s * (1.f / 65536.f);
  const float var  = ss * (1.f / 65536.f) - mean * mean;
  const float rstd = rsqrtf(var + 1e-5f);

  const float* base = x + (long)(b * 512 + g * 64) * 1024 + nc * 128;
  __shared__ float tile[64][TP];
  const int row = t >> 2, c4 = t & 3;
#pragma unroll
  for (int j = 0; j < 8; ++j) {
    float4 v = *(const float4*)(base + (long)row * 1024 + (c4 + j * 4) * 4);
    *(float4*)&tile[row][(c4 + j * 4) * 4] = v;
  }
  const int cl4 = (t & 15) * 4;
  float ga[4], be[4];
#pragma unroll
  for (int j = 0; j < 4; ++j) {
    float gm = gamma[g * 64 + cl4 + j];
    ga[j] = gm * rstd;
    be[j] = beta[g * 64 + cl4 + j] - mean * ga[j];
  }
  const float4 v1c = *(const float4*)(v1 + g * 64 + cl4);
  __syncthreads();
  short* outb = xnt + (long)b * 524288 + (long)(nc * 128) * 512 + g * 64 + cl4;
  float* cb = cadd + b * 1024 + nc * 128;
#pragma unroll
  for (int it = 0; it < 8; ++it) {
    const int tok = (t >> 4) + it * 16;
    float x0 = tile[cl4 + 0][tok] * ga[0] + be[0];
    float x1 = tile[cl4 + 1][tok] * ga[1] + be[1];
    float x2 = tile[cl4 + 2][tok] * ga[2] + be[2];
    float x3 = tile[cl4 + 3][tok] * ga[3] + be[3];
    short4v o;
    o.x = f2bf(x0); o.y = f2bf(x1); o.z = f2bf(x2); o.w = f2bf(x3);
    *(short4v*)(outb + (long)tok * 512) = o;
    float p = v1c.x * x0 + v1c.y * x1 + v1c.z * x2 + v1c.w * x3;
    p += __shfl_xor(p, 1, 64); p += __shfl_xor(p, 2, 64);
    p += __shfl_xor(p, 4, 64); p += __shfl_xor(p, 8, 64);
    if ((t & 15) == 0) atomicAdd(&cb[tok], p);
  }
}

// ---------------- fused Z/U projection GEMM (1D grid 1024, XCD-chunked)
// A = stacked [W2; W'] = [1024,512] bf16. lw: b(16) x y(8) x xg(8).
__global__ __launch_bounds__(256, 3) void zu_gemm(
    const short* __restrict__ W, const short* __restrict__ xnt,
    short* __restrict__ z_t, short* __restrict__ u) {
  __shared__ short lds[2 * BM * BK];
  const int lw = xcd_swz();
  const int b = lw >> 6, rem = lw & 63, y = rem >> 3, xg = rem & 7;
  const int which = y >> 2;
  const int m0 = y * BM;
  const int mloc0 = m0 - which * 512;
  const int n0 = xg * BM;
  const short* Bb = xnt + (long)b * 524288;
  const int tid = threadIdx.x, lane = tid & 63, w = tid >> 6;
  f32x4 acc[4][4] = {};
  gemm_core(W, Bb, lds, acc, m0, n0, 512, tid);

  const int wm = (w >> 1) * 64, wn = (w & 1) * 64;
  const int mb = mloc0 + wm + (lane >> 4) * 4;
  const int nb = n0 + wn + (lane & 15);
  if (which == 0) {
    short* C = z_t + (long)b * 524288;
#pragma unroll
    for (int i = 0; i < 4; ++i) {
      int m = mb + i * 16;
#pragma unroll
      for (int j = 0; j < 4; ++j) {
        int n = nb + j * 16;
        short4v o;
        o.x = f2bf(acc[i][j][0]);
        o.y = f2bf(acc[i][j][1]);
        o.z = f2bf(acc[i][j][2]);
        o.w = f2bf(acc[i][j][3]);
        *(short4v*)(C + (long)n * 512 + m) = o;  // [tok][c]
      }
    }
  } else {
    short* C = u + (long)b * 524288;  // [o][tok], stride 1024
#pragma unroll
    for (int i = 0; i < 4; ++i) {
#pragma unroll
      for (int r = 0; r < 4; ++r) {
        int m = mb + i * 16 + r;
#pragma unroll
        for (int j = 0; j < 4; ++j) {
          int n = nb + j * 16;
          C[(long)m * 1024 + n] = f2bf(acc[i][j][r]);
        }
      }
    }
  }
}

// ---------------- generic GEMM (S-exp / final out), 1D grid, XCD-chunked.
// bShift: log2(blocks per batch). x-tiles fixed at 8, y = rem >> 3.
template <int EPI>
__global__ __launch_bounds__(256, 3) void gemm_bt(
    const short* __restrict__ A, const short* __restrict__ Bt,
    void* __restrict__ Cv, const float* __restrict__ bias,
    const float* __restrict__ resid, float scale,
    int M, int N, int K, long aStr, long bStr, long cStr, long rStr,
    float* __restrict__ lsum, const float* __restrict__ cadd, int bShift) {
  __shared__ short lds[2 * BM * BK];
  const int lw = xcd_swz();
  const int b = lw >> bShift, rem = lw & ((1 << bShift) - 1);
  const int m0 = (rem >> 3) * BM, n0 = (rem & 7) * BM;
  const short* Ab = A + (long)b * aStr;
  const short* Bb = Bt + (long)b * bStr;
  const int tid = threadIdx.x, lane = tid & 63, w = tid >> 6;
  f32x4 acc[4][4] = {};
  gemm_core(Ab, Bb, lds, acc, m0, n0, K, tid);

  const int wm = (w >> 1) * 64, wn = (w & 1) * 64;
  const int mb = m0 + wm + (lane >> 4) * 4;
  const int nb = n0 + wn + (lane & 15);
  if constexpr (EPI == EPI_EXP_T) {
    // A=z_t (rows=key tokens), Bt=xnt (rows=query tokens).
    // P'[q][key] = exp((S + cadd[key]) * scale); rowsums -> lsum[b][q].
    short* C = (short*)Cv + (long)b * cStr;
    float4 ca[4];
#pragma unroll
    for (int i = 0; i < 4; ++i)
      ca[i] = *(const float4*)(cadd + b * 1024 + mb + i * 16);
    float rowsum[4] = {0.f, 0.f, 0.f, 0.f};
#pragma unroll
    for (int j = 0; j < 4; ++j) {
      int n = nb + j * 16;  // query
#pragma unroll
      for (int i = 0; i < 4; ++i) {
        int m = mb + i * 16;  // key
        float e0 = __expf((acc[i][j][0] + ca[i].x) * scale);
        float e1 = __expf((acc[i][j][1] + ca[i].y) * scale);
        float e2 = __expf((acc[i][j][2] + ca[i].z) * scale);
        float e3 = __expf((acc[i][j][3] + ca[i].w) * scale);
        rowsum[j] += (e0 + e1) + (e2 + e3);
        short4v o;
        o.x = f2bf(e0); o.y = f2bf(e1); o.z = f2bf(e2); o.w = f2bf(e3);
        *(short4v*)(C + (long)n * M + m) = o;
      }
    }
#pragma unroll
    for (int j = 0; j < 4; ++j) {
      rowsum[j] += __shfl_xor(rowsum[j], 16, 64);
      rowsum[j] += __shfl_xor(rowsum[j], 32, 64);
    }
    if (lane < 16) {
#pragma unroll
      for (int j = 0; j < 4; ++j)
        atomicAdd(&lsum[b * 1024 + nb + j * 16], rowsum[j]);
    }
  } else {  // EPI_OUT: A=u[o][j], Bt=P'[i][j]. out = acc/lsum[i] + bias2[o] + x
    float* C = (float*)Cv + (long)b * cStr;
    const float* R = resid + (long)b * rStr;
#pragma unroll
    for (int j = 0; j < 4; ++j) {
      int n = nb + j * 16;  // query i
      float rl = 1.0f / lsum[b * 1024 + n];
#pragma unroll
      for (int i = 0; i < 4; ++i) {
#pragma unroll
        for (int r = 0; r < 4; ++r) {
          int m = mb + i * 16 + r;  // channel o
          C[(long)m * N + n] = acc[i][j][r] * rl + bias[m] + R[(long)m * N + n];
        }
      }
    }
  }
}

// ---------------------------------------------------------------- launch
extern "C" void kernel_launch(void* const* d_in, const int* in_sizes, int n_in,
                              void* d_out, int out_size, void* d_ws, size_t ws_size,
                              hipStream_t stream) {
  const float* x     = (const float*)d_in[0];
  const float* gamma = (const float*)d_in[1];
  const float* beta  = (const float*)d_in[2];
  const float* wq    = (const float*)d_in[3];
  const float* bq    = (const float*)d_in[4];
  const float* wk    = (const float*)d_in[5];
  const float* bk    = (const float*)d_in[6];
  const float* wv    = (const float*)d_in[7];
  const float* bv    = (const float*)d_in[8];
  const float* wp    = (const float*)d_in[9];
  const float* bp    = (const float*)d_in[10];
  (void)bk;  // wq^T.bk term is query-constant -> softmax-invariant, drops out

  char* ws = (char*)d_ws;
  short* Wst   = (short*)ws;                     // [W2; W'] bf16, 1 MB
  float* bias2 = (float*)(ws + 1572864l);        // 512 f32
  float* lsum  = (float*)(ws + 1638400l);        // 16x1024 f32
  float* v1    = (float*)(ws + 1703936l);        // 512 f32
  float* cadd  = (float*)(ws + 1708032l);        // 16x1024 f32
  short* xnt = (short*)(ws + 2097152l);          // [B,N,C] bf16, 16 MB
  short* z_t = (short*)(ws + 18874368l);         // [B,tok,c]
  short* u   = (short*)(ws + 52428800l);         // [B,o,tok] bf16
  short* Sbf = (short*)(ws + 69206016l);         // [B,N,N] bf16 (P')
  // transient (all dead before sexp writes Sbf):
  float2* gnpart = (float2*)Sbf;                 // 8 KB
  short* wp_bf = Sbf + 65536;                    // 512 KB
  short* wvT   = Sbf + 327680;                   // 512 KB
  short* wqT   = Sbf + 589824;                   // 512 KB
  short* wkT   = Sbf + 851968;                   // 512 KB

  pre_kernel<<<1512, 256, 0, stream>>>(
      x, gnpart, wq, wk, wp, wv, bv, bp, wp_bf, wvT, wqT, wkT,
      bias2, lsum, cadd);

  wgemm_kernel<<<dim3(4, 10), 256, 0, stream>>>(
      wqT, wkT, wp_bf, wvT, bq, Wst, v1);

  gn_norm_t<<<1024, 256, 0, stream>>>(x, gnpart, gamma, beta, v1, xnt, cadd);

  zu_gemm<<<1024, 256, 0, stream>>>(Wst, xnt, z_t, u);

  const float iscale = 0.044194173824159216f;  // 1/sqrt(512)
  // P' = exp((z_t . xnt^T + cadd)^T * scale), rowsums -> lsum
  gemm_bt<EPI_EXP_T><<<1024, 256, 0, stream>>>(
      z_t, xnt, Sbf, nullptr, nullptr, iscale, 1024, 1024, 512,
      524288, 524288, 1048576, 0, lsum, cadd, 6);
  // out[o][i] = (u . P'^T)/lsum[i] + bias2[o] + x
  gemm_bt<EPI_OUT><<<512, 256, 0, stream>>>(
      u, Sbf, d_out, bias2, x, 1.f, 512, 1024, 1024,
      524288, 1048576, 524288, 524288, lsum, nullptr, 5);
}

// Round 15
// 108.656 us; speedup vs baseline: 1.5501x; 1.0863x over previous
//
#include <hip/hip_runtime.h>

typedef __attribute__((ext_vector_type(8))) short short8;
typedef __attribute__((ext_vector_type(4))) short short4v;
typedef __attribute__((ext_vector_type(4))) float f32x4;
typedef __attribute__((ext_vector_type(4))) int i32x4;

__device__ __forceinline__ short f2bf(float f) {
  unsigned u = __builtin_bit_cast(unsigned, f);
  u = u + 0x7fffu + ((u >> 16) & 1u);
  return (short)(u >> 16);
}
__device__ __forceinline__ int q8(float v) {
  int q = (int)rintf(v * 16.f);
  return q < -127 ? -127 : (q > 127 ? 127 : q);
}

// XCD-aware remap (gridDim.x % 8 == 0).
__device__ __forceinline__ int xcd_swz() {
  const int cpx = gridDim.x >> 3;
  return (blockIdx.x & 7) * cpx + (blockIdx.x >> 3);
}

// ---------------- fused pre (same as R14)
__global__ __launch_bounds__(256) void pre_kernel(
    const float* __restrict__ x, float2* __restrict__ part,
    const float* __restrict__ wq, const float* __restrict__ wk,
    const float* __restrict__ wp, const float* __restrict__ wv,
    const float* __restrict__ bv, const float* __restrict__ bp,
    short* __restrict__ wp_bf, short* __restrict__ wvT,
    short* __restrict__ wqT, short* __restrict__ wkT,
    float* __restrict__ bias2, float* __restrict__ lsum,
    float* __restrict__ cadd) {
  const int blk = blockIdx.x, t = threadIdx.x;
  if (blk < 32) {
    const int w = t >> 6, lane = t & 63;
    const float4 b0 = *(const float4*)(bv + lane * 8);
    const float4 b1 = *(const float4*)(bv + lane * 8 + 4);
#pragma unroll
    for (int idx = 0; idx < 4; ++idx) {
      const int m = blk * 16 + w * 4 + idx;
      const float4 a0 = *(const float4*)(wp + (long)m * 512 + lane * 8);
      const float4 a1 = *(const float4*)(wp + (long)m * 512 + lane * 8 + 4);
      float s = a0.x * b0.x + a0.y * b0.y + a0.z * b0.z + a0.w * b0.w
              + a1.x * b1.x + a1.y * b1.y + a1.z * b1.z + a1.w * b1.w;
#pragma unroll
      for (int o = 32; o > 0; o >>= 1) s += __shfl_xor(s, o, 64);
      if (lane == 0) bias2[m] = bp[m] + s;
    }
  } else if (blk < 224) {
    const float* src; short* dst; int t2;
    if (blk < 96)       { t2 = blk - 32;  src = wv; dst = wvT; }
    else if (blk < 160) { t2 = blk - 96;  src = wq; dst = wqT; }
    else                { t2 = blk - 160; src = wk; dst = wkT; }
    const int tr = t2 >> 3, tc = t2 & 7;
    __shared__ float tile[64][65];
    const int r = t >> 2, q4 = t & 3;
    const float* s4 = src + (long)(tr * 64 + r) * 512 + tc * 64 + q4 * 16;
#pragma unroll
    for (int k = 0; k < 4; ++k) {
      float4 v = ((const float4*)s4)[k];
      tile[r][q4 * 16 + k * 4 + 0] = v.x;
      tile[r][q4 * 16 + k * 4 + 1] = v.y;
      tile[r][q4 * 16 + k * 4 + 2] = v.z;
      tile[r][q4 * 16 + k * 4 + 3] = v.w;
    }
    __syncthreads();
    const int oc = t >> 2, seg = t & 3;
    short tmp[16];
#pragma unroll
    for (int e = 0; e < 16; ++e) tmp[e] = f2bf(tile[seg * 16 + e][oc]);
    short* dp = dst + (long)(tc * 64 + oc) * 512 + tr * 64 + seg * 16;
    *(short8*)dp = *(short8*)&tmp[0];
    *(short8*)(dp + 8) = *(short8*)&tmp[8];
  } else if (blk < 228) {
    float4* p = (float4*)lsum;
    const int base = (blk - 224) * 1024 + t * 4;
#pragma unroll
    for (int k = 0; k < 4; ++k) p[base + k] = make_float4(0.f, 0.f, 0.f, 0.f);
  } else if (blk < 232) {
    float4* p = (float4*)cadd;
    const int base = (blk - 228) * 1024 + t * 4;
#pragma unroll
    for (int k = 0; k < 4; ++k) p[base + k] = make_float4(0.f, 0.f, 0.f, 0.f);
  } else if (blk < 488) {
    const int i4 = (blk - 232) * 1024 + t * 4;
    float4 v = *(const float4*)(wp + i4);
    short4v o;
    o.x = f2bf(v.x); o.y = f2bf(v.y); o.z = f2bf(v.z); o.w = f2bf(v.w);
    *(short4v*)(wp_bf + i4) = o;
  } else {
    const int blk2 = blk - 488;
    const float* base = x + (long)blk2 * 8192;
    float s = 0.f, ss = 0.f;
#pragma unroll
    for (int j = 0; j < 8; ++j) {
      float4 v = ((const float4*)base)[t + j * 256];
      s  += v.x + v.y + v.z + v.w;
      ss += v.x * v.x + v.y * v.y + v.z * v.z + v.w * v.w;
    }
    for (int o = 32; o > 0; o >>= 1) { s += __shfl_xor(s, o, 64); ss += __shfl_xor(ss, o, 64); }
    __shared__ float rs[4], rss[4];
    if ((t & 63) == 0) { rs[t >> 6] = s; rss[t >> 6] = ss; }
    __syncthreads();
    if (t == 0) {
      part[blk2] = make_float2(rs[0] + rs[1] + rs[2] + rs[3],
                               rss[0] + rss[1] + rss[2] + rss[3]);
    }
  }
}

// ---------------- bf16 GEMM core (proven: single-buffer, 2-barrier, 128x128)
#define BM 128
#define BK 64
enum { EPI_OUT = 5 };

__device__ __forceinline__ int swz_idx(int row, int k) {
  return row * 64 + ((((k >> 3) ^ row) & 7) << 3) + (k & 7);
}

__device__ __forceinline__ void gemm_core(
    const short* __restrict__ Ab, const short* __restrict__ Bb,
    short* lds, f32x4 (&acc)[4][4], int m0, int n0, int K, int tid) {
  const int lane = tid & 63, w = tid >> 6;
  const int wm = (w >> 1) * 64, wn = (w & 1) * 64;
  const int rowst = w * 32 + (lane >> 3);
  for (int k0 = 0; k0 < K; k0 += BK) {
    __syncthreads();
#pragma unroll
    for (int it = 0; it < 4; ++it) {
      int ci = w * 4 + it;
      int row = rowst + it * 8;
      int slot = (lane & 7) ^ (row & 7);
      const short* ga = Ab + (long)(m0 + row) * K + k0 + slot * 8;
      __builtin_amdgcn_global_load_lds(
          (const __attribute__((address_space(1))) void*)ga,
          (__attribute__((address_space(3))) void*)(lds + ci * 512), 16, 0, 0);
      const short* gb = Bb + (long)(n0 + row) * K + k0 + slot * 8;
      __builtin_amdgcn_global_load_lds(
          (const __attribute__((address_space(1))) void*)gb,
          (__attribute__((address_space(3))) void*)(lds + 8192 + ci * 512), 16, 0, 0);
    }
    __syncthreads();
#pragma unroll
    for (int kk = 0; kk < 2; ++kk) {
      short8 af[4], bf[4];
      const int kf = kk * 32 + (lane >> 4) * 8;
#pragma unroll
      for (int i = 0; i < 4; ++i) {
        af[i] = *(const short8*)(lds + swz_idx(wm + i * 16 + (lane & 15), kf));
        bf[i] = *(const short8*)(lds + 8192 + swz_idx(wn + i * 16 + (lane & 15), kf));
      }
#pragma unroll
      for (int i = 0; i < 4; ++i)
#pragma unroll
        for (int j = 0; j < 4; ++j)
          acc[i][j] = __builtin_amdgcn_mfma_f32_16x16x32_bf16(af[i], bf[j], acc[i][j], 0, 0, 0);
    }
  }
}

// ---------------- W2 = wq^T.wk and W' = wp.wv (stacked [1024,512]) + v1
__global__ __launch_bounds__(256, 3) void wgemm_kernel(
    const short* __restrict__ wqT, const short* __restrict__ wkT,
    const short* __restrict__ wp_bf, const short* __restrict__ wvT,
    const float* __restrict__ bq, short* __restrict__ Wst,
    float* __restrict__ v1) {
  __shared__ short lds[2 * BM * BK];
  const int y = blockIdx.y, tid = threadIdx.x;
  if (y < 8) {
    const int which = y >> 2;
    const short* A  = which ? wp_bf : wqT;
    const short* Bt = which ? wvT   : wkT;
    const int m0 = (y & 3) * 128, n0 = blockIdx.x * 128;
    f32x4 acc[4][4] = {};
    gemm_core(A, Bt, lds, acc, m0, n0, 512, tid);
    const int lane = tid & 63, w = tid >> 6;
    const int wm = (w >> 1) * 64, wn = (w & 1) * 64;
    const int mb = m0 + wm + (lane >> 4) * 4;
    const int nb = n0 + wn + (lane & 15);
    short* C = Wst + which * 262144;
#pragma unroll
    for (int i = 0; i < 4; ++i)
#pragma unroll
      for (int r = 0; r < 4; ++r) {
        int m = mb + i * 16 + r;
#pragma unroll
        for (int j = 0; j < 4; ++j)
          C[(long)m * 512 + nb + j * 16] = f2bf(acc[i][j][r]);
      }
  } else {
    const int w = tid >> 6, lane = tid & 63;
    const int base_r = ((y - 8) * 4 + blockIdx.x) * 64;
    const float4 b0 = *(const float4*)(bq + lane * 8);
    const float4 b1 = *(const float4*)(bq + lane * 8 + 4);
#pragma unroll
    for (int idx = 0; idx < 16; ++idx) {
      const int c = base_r + w * 16 + idx;
      const short8 a = *(const short8*)(wkT + (long)c * 512 + lane * 8);
      float av[8];
#pragma unroll
      for (int e = 0; e < 8; ++e)
        av[e] = __builtin_bit_cast(float, ((unsigned)(unsigned short)a[e]) << 16);
      float s = av[0] * b0.x + av[1] * b0.y + av[2] * b0.z + av[3] * b0.w
              + av[4] * b1.x + av[5] * b1.y + av[6] * b1.z + av[7] * b1.w;
#pragma unroll
      for (int o = 32; o > 0; o >>= 1) s += __shfl_xor(s, o, 64);
      if (lane == 0) v1[c] = s;
    }
  }
}

// ---------------- GN pass 2: normalize + transpose (bf16 + i8) + cadd
#define TP 133
__global__ __launch_bounds__(256) void gn_norm_t(
    const float* __restrict__ x, const float2* __restrict__ part,
    const float* __restrict__ gamma, const float* __restrict__ beta,
    const float* __restrict__ v1, short* __restrict__ xnt,
    char* __restrict__ xi8, float* __restrict__ cadd) {
  const int blk = blockIdx.x;
  const int nc = blk & 7, g = (blk >> 3) & 7, b = blk >> 6;
  const int t = threadIdx.x;
  float s = 0.f, ss = 0.f;
#pragma unroll
  for (int j = 0; j < 8; ++j) {
    float2 p = part[(b * 8 + g) * 8 + j];
    s += p.x; ss += p.y;
  }
  const float mean = s * (1.f / 65536.f);
  const float var  = ss * (1.f / 65536.f) - mean * mean;
  const float rstd = rsqrtf(var + 1e-5f);

  const float* base = x + (long)(b * 512 + g * 64) * 1024 + nc * 128;
  __shared__ float tile[64][TP];
  const int row = t >> 2, c4 = t & 3;
#pragma unroll
  for (int j = 0; j < 8; ++j) {
    float4 v = *(const float4*)(base + (long)row * 1024 + (c4 + j * 4) * 4);
    *(float4*)&tile[row][(c4 + j * 4) * 4] = v;
  }
  const int cl4 = (t & 15) * 4;
  float ga[4], be[4];
#pragma unroll
  for (int j = 0; j < 4; ++j) {
    float gm = gamma[g * 64 + cl4 + j];
    ga[j] = gm * rstd;
    be[j] = beta[g * 64 + cl4 + j] - mean * ga[j];
  }
  const float4 v1c = *(const float4*)(v1 + g * 64 + cl4);
  __syncthreads();
  short* outb = xnt + (long)b * 524288 + (long)(nc * 128) * 512 + g * 64 + cl4;
  char* qb = xi8 + (long)b * 524288 + (long)(nc * 128) * 512 + g * 64 + cl4;
  float* cb = cadd + b * 1024 + nc * 128;
#pragma unroll
  for (int it = 0; it < 8; ++it) {
    const int tok = (t >> 4) + it * 16;
    float x0 = tile[cl4 + 0][tok] * ga[0] + be[0];
    float x1 = tile[cl4 + 1][tok] * ga[1] + be[1];
    float x2 = tile[cl4 + 2][tok] * ga[2] + be[2];
    float x3 = tile[cl4 + 3][tok] * ga[3] + be[3];
    short4v o;
    o.x = f2bf(x0); o.y = f2bf(x1); o.z = f2bf(x2); o.w = f2bf(x3);
    *(short4v*)(outb + (long)tok * 512) = o;
    unsigned pk = (q8(x0) & 255) | ((q8(x1) & 255) << 8)
                | ((q8(x2) & 255) << 16) | ((q8(x3) & 255) << 24);
    *(unsigned*)(qb + (long)tok * 512) = pk;
    float p = v1c.x * x0 + v1c.y * x1 + v1c.z * x2 + v1c.w * x3;
    p += __shfl_xor(p, 1, 64); p += __shfl_xor(p, 2, 64);
    p += __shfl_xor(p, 4, 64); p += __shfl_xor(p, 8, 64);
    if ((t & 15) == 0) atomicAdd(&cb[tok], p);
  }
}

// ---------------- fused Z/U projection GEMM (z -> int8, u -> bf16)
__global__ __launch_bounds__(256, 3) void zu_gemm(
    const short* __restrict__ W, const short* __restrict__ xnt,
    char* __restrict__ zi, short* __restrict__ u) {
  __shared__ short lds[2 * BM * BK];
  const int lw = xcd_swz();
  const int b = lw >> 6, rem = lw & 63, y = rem >> 3, xg = rem & 7;
  const int which = y >> 2;
  const int m0 = y * BM;
  const int mloc0 = m0 - which * 512;
  const int n0 = xg * BM;
  const short* Bb = xnt + (long)b * 524288;
  const int tid = threadIdx.x, lane = tid & 63, w = tid >> 6;
  f32x4 acc[4][4] = {};
  gemm_core(W, Bb, lds, acc, m0, n0, 512, tid);

  const int wm = (w >> 1) * 64, wn = (w & 1) * 64;
  const int mb = mloc0 + wm + (lane >> 4) * 4;
  const int nb = n0 + wn + (lane & 15);
  if (which == 0) {
    char* C = zi + (long)b * 524288;
#pragma unroll
    for (int i = 0; i < 4; ++i) {
      int m = mb + i * 16;
#pragma unroll
      for (int j = 0; j < 4; ++j) {
        int n = nb + j * 16;
        unsigned pk = (q8(acc[i][j][0]) & 255) | ((q8(acc[i][j][1]) & 255) << 8)
                    | ((q8(acc[i][j][2]) & 255) << 16) | ((q8(acc[i][j][3]) & 255) << 24);
        *(unsigned*)(C + (long)n * 512 + m) = pk;  // [tok][c] int8
      }
    }
  } else {
    short* C = u + (long)b * 524288;  // [o][tok], stride 1024
#pragma unroll
    for (int i = 0; i < 4; ++i) {
#pragma unroll
      for (int r = 0; r < 4; ++r) {
        int m = mb + i * 16 + r;
#pragma unroll
        for (int j = 0; j < 4; ++j) {
          int n = nb + j * 16;
          C[(long)m * 1024 + n] = f2bf(acc[i][j][r]);
        }
      }
    }
  }
}

// ---------------- S-exp via int8 MFMA (K=512 elems, BK=128 B, 4 K-steps)
// A = z_i8 [key][512], B = xnt_i8 [query][512]. S = acc/256.
// P'[q][key] = exp((S + cadd[key]) * scale); rowsums -> lsum[b][q].
__global__ __launch_bounds__(256, 3) void sexp_i8(
    const char* __restrict__ zi, const char* __restrict__ xi,
    short* __restrict__ S, float* __restrict__ lsum,
    const float* __restrict__ cadd, float scale) {
  __shared__ char lds[32768];  // A 16KB | B 16KB
  const int lw = xcd_swz();
  const int b = lw >> 6, rem = lw & 63;
  const int m0 = (rem >> 3) * 128, n0 = (rem & 7) * 128;
  const char* Ab = zi + (long)b * 524288;
  const char* Bb = xi + (long)b * 524288;
  const int tid = threadIdx.x, lane = tid & 63, w = tid >> 6;
  const int wm = (w >> 1) * 64, wn = (w & 1) * 64;
  i32x4 acc[4][4] = {};

  long aoff[4], boff[4];
  int ldst[4];
#pragma unroll
  for (int it = 0; it < 4; ++it) {
    const int ci = w * 4 + it;            // 0..15, 8 rows each
    const int row = ci * 8 + (lane >> 3);
    const int lg = (lane & 7) ^ (row & 7);
    aoff[it] = (long)(m0 + row) * 512 + lg * 16;
    boff[it] = (long)(n0 + row) * 512 + lg * 16;
    ldst[it] = ci * 1024 + lane * 16;     // = row*128 + (lg^(row&7))*16
  }
  const int ar = lane & 15, g4 = lane >> 4;
  for (int k0 = 0; k0 < 512; k0 += 128) {
    __syncthreads();
#pragma unroll
    for (int it = 0; it < 4; ++it) {
      __builtin_amdgcn_global_load_lds(
          (const __attribute__((address_space(1))) void*)(Ab + aoff[it] + k0),
          (__attribute__((address_space(3))) void*)(lds + ldst[it]), 16, 0, 0);
      __builtin_amdgcn_global_load_lds(
          (const __attribute__((address_space(1))) void*)(Bb + boff[it] + k0),
          (__attribute__((address_space(3))) void*)(lds + 16384 + ldst[it]), 16, 0, 0);
    }
    __syncthreads();
#pragma unroll
    for (int kk = 0; kk < 2; ++kk) {
      i32x4 af[4], bf[4];
#pragma unroll
      for (int i = 0; i < 4; ++i) {
        const int rowA = wm + i * 16 + ar;
        af[i] = *(const i32x4*)(lds + rowA * 128 + (((kk * 4 + g4) ^ (rowA & 7)) * 16));
        const int rowB = wn + i * 16 + ar;
        bf[i] = *(const i32x4*)(lds + 16384 + rowB * 128 + (((kk * 4 + g4) ^ (rowB & 7)) * 16));
      }
#pragma unroll
      for (int i = 0; i < 4; ++i)
#pragma unroll
        for (int j = 0; j < 4; ++j)
          acc[i][j] = __builtin_amdgcn_mfma_i32_16x16x64_i8(af[i], bf[j], acc[i][j], 0, 0, 0);
    }
  }

  const int mb = m0 + wm + g4 * 4;   // key
  const int nb = n0 + wn + ar;       // query
  short* C = S + (long)b * 1048576;
  float4 ca[4];
#pragma unroll
  for (int i = 0; i < 4; ++i)
    ca[i] = *(const float4*)(cadd + b * 1024 + mb + i * 16);
  float rowsum[4] = {0.f, 0.f, 0.f, 0.f};
  const float qs = 1.f / 256.f;
#pragma unroll
  for (int j = 0; j < 4; ++j) {
    int n = nb + j * 16;
#pragma unroll
    for (int i = 0; i < 4; ++i) {
      int m = mb + i * 16;
      float e0 = __expf(((float)acc[i][j][0] * qs + ca[i].x) * scale);
      float e1 = __expf(((float)acc[i][j][1] * qs + ca[i].y) * scale);
      float e2 = __expf(((float)acc[i][j][2] * qs + ca[i].z) * scale);
      float e3 = __expf(((float)acc[i][j][3] * qs + ca[i].w) * scale);
      rowsum[j] += (e0 + e1) + (e2 + e3);
      short4v o;
      o.x = f2bf(e0); o.y = f2bf(e1); o.z = f2bf(e2); o.w = f2bf(e3);
      *(short4v*)(C + (long)n * 1024 + m) = o;
    }
  }
#pragma unroll
  for (int j = 0; j < 4; ++j) {
    rowsum[j] += __shfl_xor(rowsum[j], 16, 64);
    rowsum[j] += __shfl_xor(rowsum[j], 32, 64);
  }
  if (lane < 16) {
#pragma unroll
    for (int j = 0; j < 4; ++j)
      atomicAdd(&lsum[b * 1024 + nb + j * 16], rowsum[j]);
  }
}

// ---------------- final out GEMM (bf16, XCD-chunked)
template <int EPI>
__global__ __launch_bounds__(256, 3) void gemm_bt(
    const short* __restrict__ A, const short* __restrict__ Bt,
    void* __restrict__ Cv, const float* __restrict__ bias,
    const float* __restrict__ resid, float scale,
    int M, int N, int K, long aStr, long bStr, long cStr, long rStr,
    float* __restrict__ lsum, int bShift) {
  __shared__ short lds[2 * BM * BK];
  const int lw = xcd_swz();
  const int b = lw >> bShift, rem = lw & ((1 << bShift) - 1);
  const int m0 = (rem >> 3) * BM, n0 = (rem & 7) * BM;
  const short* Ab = A + (long)b * aStr;
  const short* Bb = Bt + (long)b * bStr;
  const int tid = threadIdx.x, lane = tid & 63, w = tid >> 6;
  f32x4 acc[4][4] = {};
  gemm_core(Ab, Bb, lds, acc, m0, n0, K, tid);

  const int wm = (w >> 1) * 64, wn = (w & 1) * 64;
  const int mb = m0 + wm + (lane >> 4) * 4;
  const int nb = n0 + wn + (lane & 15);
  // EPI_OUT: A=u[o][j], Bt=P'[i][j]. out = acc/lsum[i] + bias2[o] + x
  float* C = (float*)Cv + (long)b * cStr;
  const float* R = resid + (long)b * rStr;
#pragma unroll
  for (int j = 0; j < 4; ++j) {
    int n = nb + j * 16;  // query i
    float rl = 1.0f / lsum[b * 1024 + n];
#pragma unroll
    for (int i = 0; i < 4; ++i) {
#pragma unroll
      for (int r = 0; r < 4; ++r) {
        int m = mb + i * 16 + r;  // channel o
        C[(long)m * N + n] = acc[i][j][r] * rl + bias[m] + R[(long)m * N + n];
      }
    }
  }
}

// ---------------------------------------------------------------- launch
extern "C" void kernel_launch(void* const* d_in, const int* in_sizes, int n_in,
                              void* d_out, int out_size, void* d_ws, size_t ws_size,
                              hipStream_t stream) {
  const float* x     = (const float*)d_in[0];
  const float* gamma = (const float*)d_in[1];
  const float* beta  = (const float*)d_in[2];
  const float* wq    = (const float*)d_in[3];
  const float* bq    = (const float*)d_in[4];
  const float* wk    = (const float*)d_in[5];
  const float* bk    = (const float*)d_in[6];
  const float* wv    = (const float*)d_in[7];
  const float* bv    = (const float*)d_in[8];
  const float* wp    = (const float*)d_in[9];
  const float* bp    = (const float*)d_in[10];
  (void)bk;  // wq^T.bk is query-constant -> softmax-invariant

  char* ws = (char*)d_ws;
  short* Wst   = (short*)ws;                     // [W2; W'] bf16, 1 MB
  float* bias2 = (float*)(ws + 1572864l);        // 512 f32
  float* lsum  = (float*)(ws + 1638400l);        // 16x1024 f32
  float* v1    = (float*)(ws + 1703936l);        // 512 f32
  float* cadd  = (float*)(ws + 1708032l);        // 16x1024 f32
  short* xnt   = (short*)(ws + 2097152l);        // [B,N,C] bf16, 16 MB
  char*  z_i8  = (char*)(ws + 18874368l);        // [B,tok,c] i8, 8.4 MB
  char*  x_i8  = (char*)(ws + 35651584l);        // [B,tok,c] i8, 8.4 MB
  short* u     = (short*)(ws + 52428800l);       // [B,o,tok] bf16
  short* Sbf   = (short*)(ws + 69206016l);       // [B,N,N] bf16 (P')
  // transient (all dead before sexp writes Sbf):
  float2* gnpart = (float2*)Sbf;                 // 8 KB
  short* wp_bf = Sbf + 65536;                    // 512 KB
  short* wvT   = Sbf + 327680;                   // 512 KB
  short* wqT   = Sbf + 589824;                   // 512 KB
  short* wkT   = Sbf + 851968;                   // 512 KB

  pre_kernel<<<1512, 256, 0, stream>>>(
      x, gnpart, wq, wk, wp, wv, bv, bp, wp_bf, wvT, wqT, wkT,
      bias2, lsum, cadd);

  wgemm_kernel<<<dim3(4, 10), 256, 0, stream>>>(
      wqT, wkT, wp_bf, wvT, bq, Wst, v1);

  gn_norm_t<<<1024, 256, 0, stream>>>(
      x, gnpart, gamma, beta, v1, xnt, x_i8, cadd);

  zu_gemm<<<1024, 256, 0, stream>>>(Wst, xnt, z_i8, u);

  const float iscale = 0.044194173824159216f;  // 1/sqrt(512)
  sexp_i8<<<1024, 256, 0, stream>>>(z_i8, x_i8, Sbf, lsum, cadd, iscale);

  // out[o][i] = (u . P'^T)/lsum[i] + bias2[o] + x
  gemm_bt<EPI_OUT><<<512, 256, 0, stream>>>(
      u, Sbf, d_out, bias2, x, 1.f, 512, 1024, 1024,
      524288, 1048576, 524288, 524288, lsum, 5);
}